// Round 2
// 261.704 us; speedup vs baseline: 1.0850x; 1.0850x over previous
//
#include <hip/hip_runtime.h>
#include <math.h>

#define B_ 2
#define S_ 2048
#define E_ 1024
#define H_ 16
#define HD_ 64
#define LAMBDA_INIT 0.8f
#define EPS_ 1e-6f

typedef __attribute__((ext_vector_type(8))) short short8;   // 8 bf16 (4 VGPRs)
typedef __attribute__((ext_vector_type(4))) float floatx4;  // MFMA C/D 16x16
typedef __attribute__((ext_vector_type(16))) float floatx16; // MFMA C/D 32x32

__device__ __forceinline__ unsigned short f2bf(float f) {
  unsigned u = __float_as_uint(f);
  u += 0x7FFFu + ((u >> 16) & 1u);   // RNE
  return (unsigned short)(u >> 16);
}

__device__ __forceinline__ void gl_lds16(const void* g, void* l) {
  __builtin_amdgcn_global_load_lds((const __attribute__((address_space(1))) void*)g,
                                   (__attribute__((address_space(3))) void*)l,
                                   16, 0, 0);
}

// ---------------------------------------------------------------------------
// cast fp32 -> bf16, contiguous
// ---------------------------------------------------------------------------
__global__ __launch_bounds__(256) void cast_bf16(const float* __restrict__ in,
                                                 unsigned short* __restrict__ out,
                                                 int n4) {
  for (int i = blockIdx.x * 256 + threadIdx.x; i < n4; i += gridDim.x * 256) {
    float4 v = ((const float4*)in)[i];
    ushort4 w;
    w.x = f2bf(v.x); w.y = f2bf(v.y); w.z = f2bf(v.z); w.w = f2bf(v.w);
    ((ushort4*)out)[i] = w;
  }
}

// ---------------------------------------------------------------------------
// transpose + cast: in fp32 [R][C] -> out bf16 [C][R]
// ---------------------------------------------------------------------------
__global__ __launch_bounds__(256) void transpose_cast(const float* __restrict__ in,
                                                      unsigned short* __restrict__ out,
                                                      int R, int C) {
  __shared__ float tile[64][65];
  const int tid = threadIdx.x;
  const int c0 = blockIdx.x * 64;
  const int r0 = blockIdx.y * 64;
#pragma unroll
  for (int it = 0; it < 16; it++) {
    int e = tid + it * 256;
    int rr = e >> 6, cc = e & 63;
    tile[rr][cc] = in[(size_t)(r0 + rr) * C + c0 + cc];
  }
  __syncthreads();
#pragma unroll
  for (int it = 0; it < 16; it++) {
    int e = tid + it * 256;
    int rr = e >> 6, cc = e & 63;
    out[(size_t)(c0 + rr) * R + r0 + cc] = f2bf(tile[cc][rr]);
  }
}

// ---------------------------------------------------------------------------
// bf16 MFMA GEMM: C[M][N] = A[M][K] @ B[K][N], B given TRANSPOSED as Bt[N][K].
// 128x128 tile, BK=64, 256 thr (4 waves, 2x2 of 64x64), global_load_lds w=16,
// XOR chunk swizzle (c_phys = c_log ^ (r&7)) -> ds_read_b128 frags <=2-way.
// ---------------------------------------------------------------------------
template <bool BF16OUT>
__global__ __launch_bounds__(256) void gemm_bt(const unsigned short* __restrict__ A,
                                               const unsigned short* __restrict__ Bt,
                                               void* __restrict__ C,
                                               int M, int N, int K) {
  __shared__ __align__(16) unsigned short As[128 * 64];
  __shared__ __align__(16) unsigned short Bs[128 * 64];
  const int tid = threadIdx.x;
  const int wave = tid >> 6, lane = tid & 63;
  const int lane15 = lane & 15, quad = lane >> 4;
  const int m0 = blockIdx.y * 128;
  const int n0 = blockIdx.x * 128;
  const int wm = (wave & 1) * 64, wn = (wave >> 1) * 64;

  floatx4 acc[4][4];
#pragma unroll
  for (int mi = 0; mi < 4; mi++)
#pragma unroll
    for (int ni = 0; ni < 4; ni++) acc[mi][ni] = (floatx4)0.0f;

  const int rs = wave * 32 + (lane >> 3);   // staging row base (+j*8)
  const int cph = lane & 7;                 // physical chunk this lane fills

  for (int k0 = 0; k0 < K; k0 += 64) {
    __syncthreads();   // prior iter's fragment reads done
#pragma unroll
    for (int j = 0; j < 4; j++) {
      int r = rs + j * 8;
      int cl = cph ^ (r & 7);
      gl_lds16(A + (size_t)(m0 + r) * K + k0 + cl * 8, &As[(wave * 32 + j * 8) * 64]);
    }
#pragma unroll
    for (int j = 0; j < 4; j++) {
      int r = rs + j * 8;
      int cl = cph ^ (r & 7);
      gl_lds16(Bt + (size_t)(n0 + r) * K + k0 + cl * 8, &Bs[(wave * 32 + j * 8) * 64]);
    }
    __syncthreads();   // drains vmcnt(0): staged data visible

#pragma unroll
    for (int ks = 0; ks < 2; ks++) {
      short8 af[4], bf[4];
#pragma unroll
      for (int mi = 0; mi < 4; mi++) {
        int r = wm + mi * 16 + lane15;
        int phys = (ks * 4 + quad) ^ (r & 7);
        af[mi] = *(const short8*)(&As[r * 64 + phys * 8]);
      }
#pragma unroll
      for (int ni = 0; ni < 4; ni++) {
        int r = wn + ni * 16 + lane15;
        int phys = (ks * 4 + quad) ^ (r & 7);
        bf[ni] = *(const short8*)(&Bs[r * 64 + phys * 8]);
      }
#pragma unroll
      for (int mi = 0; mi < 4; mi++)
#pragma unroll
        for (int ni = 0; ni < 4; ni++)
          acc[mi][ni] = __builtin_amdgcn_mfma_f32_16x16x32_bf16(af[mi], bf[ni],
                                                                acc[mi][ni], 0, 0, 0);
    }
  }

#pragma unroll
  for (int mi = 0; mi < 4; mi++)
#pragma unroll
    for (int ni = 0; ni < 4; ni++)
#pragma unroll
      for (int reg = 0; reg < 4; reg++) {
        int row = m0 + wm + mi * 16 + quad * 4 + reg;
        int col = n0 + wn + ni * 16 + lane15;
        float v = acc[mi][ni][reg];
        if (BF16OUT)
          ((unsigned short*)C)[(size_t)row * N + col] = f2bf(v);
        else
          ((float*)C)[(size_t)row * N + col] = v;
      }
}

// ---------------------------------------------------------------------------
// MFMA flash differential attention, 32x32x16 swapped-QK^T structure.
// Block = 128 q rows, 4 waves (each wave owns 32 q rows). K/V double-buffered
// in LDS via global_load_lds (XOR chunk swizzle). P never touches LDS:
// swapped QK^T puts the full P column for q=lane&31 in registers; cvt_pk_bf16 +
// v_permlane32_swap_b32 (dst.hi <-> src.lo) redistribute k-quads into PV
// A-fragments: swap(dst=w0, src=w2) -> w0={lo:(0,1),hi:(8,9)} = frag dword0,
//                                      w2={lo:(4,5),hi:(12,13)} = frag dword2.
// ---------------------------------------------------------------------------
__global__ __launch_bounds__(256) void flash_attn_mfma(
    const unsigned short* __restrict__ qkB, const unsigned short* __restrict__ vTB,
    const float* __restrict__ lq1, const float* __restrict__ lq2,
    const float* __restrict__ lk1, const float* __restrict__ lk2,
    const float* __restrict__ norm_w, float* __restrict__ out_n) {
  __shared__ __align__(16) unsigned short Ks[2][64 * 64];
  __shared__ __align__(16) unsigned short Vs[2][64 * 64];

  const int tid = threadIdx.x;
  const int wave = tid >> 6, lane = tid & 63;
  const int l31 = lane & 31, hi = lane >> 5;

  // bijective XCD swizzle: the 16 q-tiles sharing one (b,h)'s K/V land on one XCD
  const int bid = (blockIdx.x & 7) * 64 + (blockIdx.x >> 3);   // 512 blocks
  const int qt = bid & 15;
  const int h = (bid >> 4) & 15;
  const int b = bid >> 8;
  const int q0 = qt * 128;

  float a1 = 0.f, a2 = 0.f;
  for (int d = 0; d < HD_; d++) {
    a1 += lq1[d] * lk1[d];
    a2 += lq2[d] * lk2[d];
  }
  const float lam = __expf(a1) - __expf(a2) + LAMBDA_INIT;

  // Q fragments direct from global: Q[q = q0+wave*32+l31][ch = s*32+cs*16+hi*8 ..+7]
  short8 qf[2][2];
  {
    const unsigned short* qrow =
        qkB + (size_t)(b * S_ + q0 + wave * 32 + l31) * 2048 + h * 64;
#pragma unroll
    for (int s = 0; s < 2; s++)
#pragma unroll
      for (int cs = 0; cs < 2; cs++)
        qf[s][cs] = *(const short8*)(qrow + s * 32 + cs * 16 + hi * 8);
  }

  floatx16 accO[2][2];
#pragma unroll
  for (int s = 0; s < 2; s++)
#pragma unroll
    for (int n = 0; n < 2; n++) accO[s][n] = (floatx16)0.0f;
  float lsum[2] = {0.f, 0.f};
  const floatx16 zero16 = (floatx16)0.0f;

  const int srow = tid >> 3;   // staging row within a 32-row round
  const int scol = tid & 7;    // physical 16B chunk this lane fills
  const size_t kgbase = (size_t)(b * S_) * 2048 + 1024 + h * 64;
  const size_t vgbase = (size_t)h * 64 * 4096 + b * 2048;

  // prologue: stage tile 0 into buffer 0
#pragma unroll
  for (int rnd = 0; rnd < 2; rnd++) {
    int r = rnd * 32 + srow;
    int cl = scol ^ (r & 7);
    gl_lds16(qkB + kgbase + (size_t)r * 2048 + cl * 8,
             &Ks[0][(rnd * 32 + wave * 8) * 64]);
    gl_lds16(vTB + vgbase + (size_t)r * 4096 + cl * 8,
             &Vs[0][(rnd * 32 + wave * 8) * 64]);
  }
  __syncthreads();

  int cur = 0;
  for (int t = 0; t < S_ / 64; t++) {
    if (t < S_ / 64 - 1) {   // stage next tile into alternate buffer (async)
      const size_t kg = kgbase + (size_t)(t + 1) * 64 * 2048;
      const size_t vg = vgbase + (size_t)(t + 1) * 64;
#pragma unroll
      for (int rnd = 0; rnd < 2; rnd++) {
        int r = rnd * 32 + srow;
        int cl = scol ^ (r & 7);
        gl_lds16(qkB + kg + (size_t)r * 2048 + cl * 8,
                 &Ks[cur ^ 1][(rnd * 32 + wave * 8) * 64]);
        gl_lds16(vTB + vg + (size_t)r * 4096 + cl * 8,
                 &Vs[cur ^ 1][(rnd * 32 + wave * 8) * 64]);
      }
    }
    const unsigned short* Kc = Ks[cur];
    const unsigned short* Vc = Vs[cur];

#pragma unroll
    for (int kb = 0; kb < 2; kb++) {
      const int krow = kb * 32 + l31;
      const int kx = krow & 7;
      short8 pf[2][2];   // [s][ks2] PV A-fragments
#pragma unroll
      for (int s = 0; s < 2; s++) {
        floatx16 accS = zero16;
#pragma unroll
        for (int cs = 0; cs < 2; cs++) {
          const int pc = (s * 4 + cs * 2 + hi) ^ kx;
          const short8 kf = *(const short8*)(Kc + krow * 64 + pc * 8);
          accS = __builtin_amdgcn_mfma_f32_32x32x16_bf16(kf, qf[s][cs], accS, 0, 0, 0);
        }
        // accS: q = l31 (col), k row = (reg&3) + 8*(reg>>2) + 4*hi
        unsigned w[8];
        float ls = 0.f;
#pragma unroll
        for (int i = 0; i < 8; i++) {
          float p0 = __expf(accS[2 * i] * 0.125f);
          float p1 = __expf(accS[2 * i + 1] * 0.125f);
          ls += p0 + p1;
          asm("v_cvt_pk_bf16_f32 %0, %1, %2" : "=v"(w[i]) : "v"(p0), "v"(p1));
        }
        lsum[s] += ls;
        // dst.hi <-> src.lo: dst = low k-quad pack, src = high k-quad pack
        asm volatile("v_permlane32_swap_b32 %0, %1" : "+v"(w[0]), "+v"(w[2]));
        asm volatile("v_permlane32_swap_b32 %0, %1" : "+v"(w[1]), "+v"(w[3]));
        asm volatile("v_permlane32_swap_b32 %0, %1" : "+v"(w[4]), "+v"(w[6]));
        asm volatile("v_permlane32_swap_b32 %0, %1" : "+v"(w[5]), "+v"(w[7]));
        uint4 u0 = make_uint4(w[0], w[1], w[2], w[3]);
        uint4 u1 = make_uint4(w[4], w[5], w[6], w[7]);
        pf[s][0] = __builtin_bit_cast(short8, u0);
        pf[s][1] = __builtin_bit_cast(short8, u1);
      }
      // PV: V fragment shared across both s (halves the V ds_reads)
#pragma unroll
      for (int ks2 = 0; ks2 < 2; ks2++)
#pragma unroll
        for (int n = 0; n < 2; n++) {
          const int vrow = n * 32 + l31;
          const int pc = (kb * 4 + ks2 * 2 + hi) ^ (vrow & 7);
          const short8 vf = *(const short8*)(Vc + vrow * 64 + pc * 8);
          accO[0][n] = __builtin_amdgcn_mfma_f32_32x32x16_bf16(pf[0][ks2], vf,
                                                               accO[0][n], 0, 0, 0);
          accO[1][n] = __builtin_amdgcn_mfma_f32_32x32x16_bf16(pf[1][ks2], vf,
                                                               accO[1][n], 0, 0, 0);
        }
    }
    __syncthreads();   // drains vmcnt(0): next tile staged; cur free to overwrite
    cur ^= 1;
  }

  // epilogue: finalize row sums (partner half holds complementary k rows)
  lsum[0] += __shfl_xor(lsum[0], 32, 64);
  lsum[1] += __shfl_xor(lsum[1], 32, 64);
  const float* nw = norm_w + h * HD_;
  const float nw0 = nw[l31], nw1 = nw[32 + l31];
#pragma unroll
  for (int r = 0; r < 16; r++) {
    const int qr = (r & 3) + 8 * (r >> 2) + 4 * hi;   // q row within wave's 32
    const float s1 = __shfl(lsum[0], qr, 64);
    const float s2 = __shfl(lsum[1], qr, 64);
    const float inv1 = 1.0f / s1;
    const float c2 = lam / s2;
    float o0 = accO[0][0][r] * inv1 - accO[1][0][r] * c2;   // d = l31
    float o1 = accO[0][1][r] * inv1 - accO[1][1][r] * c2;   // d = 32 + l31
    float ss = o0 * o0 + o1 * o1;
#pragma unroll
    for (int msk = 1; msk <= 16; msk <<= 1) ss += __shfl_xor(ss, msk, 64);
    const float rsc = (1.0f - LAMBDA_INIT) * rsqrtf(ss * (1.0f / 64.0f) + EPS_);
    float* dst = out_n + ((size_t)(b * H_ + h) * S_ + q0 + wave * 32 + qr) * HD_;
    dst[l31] = o0 * rsc * nw0;
    dst[32 + l31] = o1 * rsc * nw1;
  }
}

// ---------------------------------------------------------------------------
// Reshape out_n [B,H,S,HD] fp32 -> hidden bf16 (reference cat/transpose/view)
// ---------------------------------------------------------------------------
__global__ __launch_bounds__(256) void reshape_out(const float* __restrict__ out_n,
                                                   unsigned short* __restrict__ hidden) {
  __shared__ float tile[64][65];
  const int tid = threadIdx.x;
  const int bi = blockIdx.x;  // B*H*32 = 1024
  const int tb = bi & 31;
  const int h = (bi >> 5) & 15;
  const int b = bi >> 9;
  const int t0 = tb * 64;
  const float* src = out_n + (((size_t)b * H_ + h) * S_ + t0) * HD_;
#pragma unroll
  for (int rr = 0; rr < 16; rr++) {
    int e = tid + rr * 256;
    tile[e >> 6][e & 63] = src[e];
  }
  __syncthreads();
  unsigned short* dst = hidden + (size_t)b * (S_ * E_) + h * S_ + t0;
#pragma unroll
  for (int rr = 0; rr < 16; rr++) {
    int e = tid + rr * 256;
    int d = e >> 6, tt = e & 63;
    dst[(size_t)d * (H_ * S_) + tt] = f2bf(tile[tt][d]);
  }
}

// ---------------------------------------------------------------------------
extern "C" void kernel_launch(void* const* d_in, const int* in_sizes, int n_in,
                              void* d_out, int out_size, void* d_ws, size_t ws_size,
                              hipStream_t stream) {
  const float* x = (const float*)d_in[0];
  const float* w_qkv = (const float*)d_in[1];
  const float* wo = (const float*)d_in[2];
  const float* lq1 = (const float*)d_in[3];
  const float* lq2 = (const float*)d_in[4];
  const float* lk1 = (const float*)d_in[5];
  const float* lk2 = (const float*)d_in[6];
  const float* norm_w = (const float*)d_in[7];
  float* out = (float*)d_out;

  unsigned short* xB = (unsigned short*)d_ws;             // 4096*1024
  unsigned short* WT = xB + (size_t)4096 * 1024;          // 3072*1024 (w_qkv^T)
  unsigned short* woT = WT + (size_t)3072 * 1024;         // 1024*1024
  unsigned short* qkB = woT + (size_t)1024 * 1024;        // 4096*2048
  unsigned short* vTB = qkB + (size_t)4096 * 2048;        // 1024*4096
  unsigned short* hidB = vTB + (size_t)1024 * 4096;       // 4096*1024
  float* out_n = (float*)(hidB + (size_t)4096 * 1024);    // 4 Mi floats

  // 0) bf16 casts / transposes of inputs
  cast_bf16<<<1024, 256, 0, stream>>>(x, xB, 4096 * 1024 / 4);
  transpose_cast<<<dim3(48, 16), 256, 0, stream>>>(w_qkv, WT, 1024, 3072);
  transpose_cast<<<dim3(16, 16), 256, 0, stream>>>(wo, woT, 1024, 1024);

  // 1a) q,k = x @ Wqk      -> qkB bf16 [4096][2048]
  gemm_bt<true><<<dim3(2048 / 128, 4096 / 128), 256, 0, stream>>>(
      xB, WT, (void*)qkB, 4096, 2048, 1024);
  // 1b) vT = Wv^T @ x^T    -> vTB bf16 [1024][4096]  (operand swap: free transpose)
  gemm_bt<true><<<dim3(4096 / 128, 1024 / 128), 256, 0, stream>>>(
      WT + (size_t)2048 * 1024, xB, (void*)vTB, 1024, 4096, 1024);

  // 2) MFMA differential flash attention + RMSNorm (128 q rows / block)
  flash_attn_mfma<<<B_ * H_ * (S_ / 128), 256, 0, stream>>>(qkB, vTB, lq1, lq2, lk1,
                                                            lk2, norm_w, out_n);
  // 3) reshape per reference's cat/transpose/view -> bf16
  reshape_out<<<B_ * H_ * (S_ / 64), 256, 0, stream>>>(out_n, hidB);
  // 4) out = hidden @ wo (fp32 out)
  gemm_bt<false><<<dim3(1024 / 128, 4096 / 128), 256, 0, stream>>>(
      hidB, woT, (void*)out, 4096, 1024, 1024);
}

// Round 6
// 251.821 us; speedup vs baseline: 1.1276x; 1.0392x over previous
//
#include <hip/hip_runtime.h>
#include <math.h>

#define B_ 2
#define S_ 2048
#define E_ 1024
#define H_ 16
#define HD_ 64
#define LAMBDA_INIT 0.8f
#define EPS_ 1e-6f

typedef __attribute__((ext_vector_type(8))) short short8;   // 8 bf16 (4 VGPRs)
typedef __attribute__((ext_vector_type(4))) float floatx4;  // MFMA C/D 16x16
typedef __attribute__((ext_vector_type(16))) float floatx16; // MFMA C/D 32x32

__device__ __forceinline__ unsigned short f2bf(float f) {
  unsigned u = __float_as_uint(f);
  u += 0x7FFFu + ((u >> 16) & 1u);   // RNE
  return (unsigned short)(u >> 16);
}

__device__ __forceinline__ void gl_lds16(const void* g, void* l) {
  __builtin_amdgcn_global_load_lds((const __attribute__((address_space(1))) void*)g,
                                   (__attribute__((address_space(3))) void*)l,
                                   16, 0, 0);
}

// ---------------------------------------------------------------------------
// cast fp32 -> bf16, contiguous
// ---------------------------------------------------------------------------
__global__ __launch_bounds__(256) void cast_bf16(const float* __restrict__ in,
                                                 unsigned short* __restrict__ out,
                                                 int n4) {
  for (int i = blockIdx.x * 256 + threadIdx.x; i < n4; i += gridDim.x * 256) {
    float4 v = ((const float4*)in)[i];
    ushort4 w;
    w.x = f2bf(v.x); w.y = f2bf(v.y); w.z = f2bf(v.z); w.w = f2bf(v.w);
    ((ushort4*)out)[i] = w;
  }
}

// ---------------------------------------------------------------------------
// transpose + cast: in fp32 [R][C] -> out bf16 [C][R]
// ---------------------------------------------------------------------------
__global__ __launch_bounds__(256) void transpose_cast(const float* __restrict__ in,
                                                      unsigned short* __restrict__ out,
                                                      int R, int C) {
  __shared__ float tile[64][65];
  const int tid = threadIdx.x;
  const int c0 = blockIdx.x * 64;
  const int r0 = blockIdx.y * 64;
#pragma unroll
  for (int it = 0; it < 16; it++) {
    int e = tid + it * 256;
    int rr = e >> 6, cc = e & 63;
    tile[rr][cc] = in[(size_t)(r0 + rr) * C + c0 + cc];
  }
  __syncthreads();
#pragma unroll
  for (int it = 0; it < 16; it++) {
    int e = tid + it * 256;
    int rr = e >> 6, cc = e & 63;
    out[(size_t)(c0 + rr) * R + r0 + cc] = f2bf(tile[cc][rr]);
  }
}

// ---------------------------------------------------------------------------
// bf16 MFMA GEMM: C[M][N] = A[M][K] @ B[K][N], B given TRANSPOSED as Bt[N][K].
// Tile 128 x BNT (BNT = 128 or 64), BK=64, 256 thr (4 waves, 2x2 of
// 64 x BNT/2), global_load_lds w=16, XOR chunk swizzle (c_phys = c_log^(r&7))
// -> ds_read_b128 frags <=2-way. BNT=64 doubles block count for skinny-N
// GEMMs (1 -> 2 blocks/CU): K-accumulation order unchanged -> bitwise-same C.
// ---------------------------------------------------------------------------
template <bool BF16OUT, int BNT>
__global__ __launch_bounds__(256, BNT == 64 ? 2 : 1) void gemm_bt(
    const unsigned short* __restrict__ A, const unsigned short* __restrict__ Bt,
    void* __restrict__ C, int M, int N, int K) {
  __shared__ __align__(16) unsigned short As[128 * 64];
  __shared__ __align__(16) unsigned short Bs[BNT * 64];
  const int tid = threadIdx.x;
  const int wave = tid >> 6, lane = tid & 63;
  const int lane15 = lane & 15, quad = lane >> 4;
  const int m0 = blockIdx.y * 128;
  const int n0 = blockIdx.x * BNT;
  const int wm = (wave & 1) * 64, wn = (wave >> 1) * (BNT / 2);
  const int NI = BNT / 32;   // n-fragments per wave

  floatx4 acc[4][NI];
#pragma unroll
  for (int mi = 0; mi < 4; mi++)
#pragma unroll
    for (int ni = 0; ni < NI; ni++) acc[mi][ni] = (floatx4)0.0f;

  const int rsA = wave * 32 + (lane >> 3);        // A staging row base (+j*8)
  const int rsB = wave * (BNT / 4) + (lane >> 3); // B staging row base (+j*8)
  const int cph = lane & 7;                       // physical chunk this lane fills

  for (int k0 = 0; k0 < K; k0 += 64) {
    __syncthreads();   // prior iter's fragment reads done
#pragma unroll
    for (int j = 0; j < 4; j++) {
      int r = rsA + j * 8;
      int cl = cph ^ (r & 7);
      gl_lds16(A + (size_t)(m0 + r) * K + k0 + cl * 8, &As[(wave * 32 + j * 8) * 64]);
    }
#pragma unroll
    for (int j = 0; j < BNT / 32; j++) {
      int r = rsB + j * 8;
      int cl = cph ^ (r & 7);
      gl_lds16(Bt + (size_t)(n0 + r) * K + k0 + cl * 8,
               &Bs[(wave * (BNT / 4) + j * 8) * 64]);
    }
    __syncthreads();   // drains vmcnt(0): staged data visible

#pragma unroll
    for (int ks = 0; ks < 2; ks++) {
      short8 af[4], bf[NI];
#pragma unroll
      for (int mi = 0; mi < 4; mi++) {
        int r = wm + mi * 16 + lane15;
        int phys = (ks * 4 + quad) ^ (r & 7);
        af[mi] = *(const short8*)(&As[r * 64 + phys * 8]);
      }
#pragma unroll
      for (int ni = 0; ni < NI; ni++) {
        int r = wn + ni * 16 + lane15;
        int phys = (ks * 4 + quad) ^ (r & 7);
        bf[ni] = *(const short8*)(&Bs[r * 64 + phys * 8]);
      }
#pragma unroll
      for (int mi = 0; mi < 4; mi++)
#pragma unroll
        for (int ni = 0; ni < NI; ni++)
          acc[mi][ni] = __builtin_amdgcn_mfma_f32_16x16x32_bf16(af[mi], bf[ni],
                                                                acc[mi][ni], 0, 0, 0);
    }
  }

#pragma unroll
  for (int mi = 0; mi < 4; mi++)
#pragma unroll
    for (int ni = 0; ni < NI; ni++)
#pragma unroll
      for (int reg = 0; reg < 4; reg++) {
        int row = m0 + wm + mi * 16 + quad * 4 + reg;
        int col = n0 + wn + ni * 16 + lane15;
        float v = acc[mi][ni][reg];
        if (BF16OUT)
          ((unsigned short*)C)[(size_t)row * N + col] = f2bf(v);
        else
          ((float*)C)[(size_t)row * N + col] = v;
      }
}

// ---------------------------------------------------------------------------
// MFMA flash differential attention, 32x32x16 swapped-QK^T structure.
// Block = 128 q rows, 4 waves (each wave owns 32 q rows). K/V double-buffered
// in LDS via global_load_lds (XOR chunk swizzle). P never touches LDS:
// swapped QK^T puts the full P column for q=lane&31 in registers; cvt_pk_bf16 +
// v_permlane32_swap_b32 (dst.hi <-> src.lo) redistribute k-quads into PV
// A-fragments. [VERIFIED R2 VERSION -- byte-identical; do not edit blind:
// R3/R4/R5 deltas here all failed correctness.]
// ---------------------------------------------------------------------------
__global__ __launch_bounds__(256) void flash_attn_mfma(
    const unsigned short* __restrict__ qkB, const unsigned short* __restrict__ vTB,
    const float* __restrict__ lq1, const float* __restrict__ lq2,
    const float* __restrict__ lk1, const float* __restrict__ lk2,
    const float* __restrict__ norm_w, float* __restrict__ out_n) {
  __shared__ __align__(16) unsigned short Ks[2][64 * 64];
  __shared__ __align__(16) unsigned short Vs[2][64 * 64];

  const int tid = threadIdx.x;
  const int wave = tid >> 6, lane = tid & 63;
  const int l31 = lane & 31, hi = lane >> 5;

  // bijective XCD swizzle: the 16 q-tiles sharing one (b,h)'s K/V land on one XCD
  const int bid = (blockIdx.x & 7) * 64 + (blockIdx.x >> 3);   // 512 blocks
  const int qt = bid & 15;
  const int h = (bid >> 4) & 15;
  const int b = bid >> 8;
  const int q0 = qt * 128;

  float a1 = 0.f, a2 = 0.f;
  for (int d = 0; d < HD_; d++) {
    a1 += lq1[d] * lk1[d];
    a2 += lq2[d] * lk2[d];
  }
  const float lam = __expf(a1) - __expf(a2) + LAMBDA_INIT;

  // Q fragments direct from global: Q[q = q0+wave*32+l31][ch = s*32+cs*16+hi*8 ..+7]
  short8 qf[2][2];
  {
    const unsigned short* qrow =
        qkB + (size_t)(b * S_ + q0 + wave * 32 + l31) * 2048 + h * 64;
#pragma unroll
    for (int s = 0; s < 2; s++)
#pragma unroll
      for (int cs = 0; cs < 2; cs++)
        qf[s][cs] = *(const short8*)(qrow + s * 32 + cs * 16 + hi * 8);
  }

  floatx16 accO[2][2];
#pragma unroll
  for (int s = 0; s < 2; s++)
#pragma unroll
    for (int n = 0; n < 2; n++) accO[s][n] = (floatx16)0.0f;
  float lsum[2] = {0.f, 0.f};
  const floatx16 zero16 = (floatx16)0.0f;

  const int srow = tid >> 3;   // staging row within a 32-row round
  const int scol = tid & 7;    // physical 16B chunk this lane fills
  const size_t kgbase = (size_t)(b * S_) * 2048 + 1024 + h * 64;
  const size_t vgbase = (size_t)h * 64 * 4096 + b * 2048;

  // prologue: stage tile 0 into buffer 0
#pragma unroll
  for (int rnd = 0; rnd < 2; rnd++) {
    int r = rnd * 32 + srow;
    int cl = scol ^ (r & 7);
    gl_lds16(qkB + kgbase + (size_t)r * 2048 + cl * 8,
             &Ks[0][(rnd * 32 + wave * 8) * 64]);
    gl_lds16(vTB + vgbase + (size_t)r * 4096 + cl * 8,
             &Vs[0][(rnd * 32 + wave * 8) * 64]);
  }
  __syncthreads();

  int cur = 0;
  for (int t = 0; t < S_ / 64; t++) {
    if (t < S_ / 64 - 1) {   // stage next tile into alternate buffer (async)
      const size_t kg = kgbase + (size_t)(t + 1) * 64 * 2048;
      const size_t vg = vgbase + (size_t)(t + 1) * 64;
#pragma unroll
      for (int rnd = 0; rnd < 2; rnd++) {
        int r = rnd * 32 + srow;
        int cl = scol ^ (r & 7);
        gl_lds16(qkB + kg + (size_t)r * 2048 + cl * 8,
                 &Ks[cur ^ 1][(rnd * 32 + wave * 8) * 64]);
        gl_lds16(vTB + vg + (size_t)r * 4096 + cl * 8,
                 &Vs[cur ^ 1][(rnd * 32 + wave * 8) * 64]);
      }
    }
    const unsigned short* Kc = Ks[cur];
    const unsigned short* Vc = Vs[cur];

#pragma unroll
    for (int kb = 0; kb < 2; kb++) {
      const int krow = kb * 32 + l31;
      const int kx = krow & 7;
      short8 pf[2][2];   // [s][ks2] PV A-fragments
#pragma unroll
      for (int s = 0; s < 2; s++) {
        floatx16 accS = zero16;
#pragma unroll
        for (int cs = 0; cs < 2; cs++) {
          const int pc = (s * 4 + cs * 2 + hi) ^ kx;
          const short8 kf = *(const short8*)(Kc + krow * 64 + pc * 8);
          accS = __builtin_amdgcn_mfma_f32_32x32x16_bf16(kf, qf[s][cs], accS, 0, 0, 0);
        }
        // accS: q = l31 (col), k row = (reg&3) + 8*(reg>>2) + 4*hi
        unsigned w[8];
        float ls = 0.f;
#pragma unroll
        for (int i = 0; i < 8; i++) {
          float p0 = __expf(accS[2 * i] * 0.125f);
          float p1 = __expf(accS[2 * i + 1] * 0.125f);
          ls += p0 + p1;
          asm("v_cvt_pk_bf16_f32 %0, %1, %2" : "=v"(w[i]) : "v"(p0), "v"(p1));
        }
        lsum[s] += ls;
        // dst.hi <-> src.lo: dst = low k-quad pack, src = high k-quad pack
        asm volatile("v_permlane32_swap_b32 %0, %1" : "+v"(w[0]), "+v"(w[2]));
        asm volatile("v_permlane32_swap_b32 %0, %1" : "+v"(w[1]), "+v"(w[3]));
        asm volatile("v_permlane32_swap_b32 %0, %1" : "+v"(w[4]), "+v"(w[6]));
        asm volatile("v_permlane32_swap_b32 %0, %1" : "+v"(w[5]), "+v"(w[7]));
        uint4 u0 = make_uint4(w[0], w[1], w[2], w[3]);
        uint4 u1 = make_uint4(w[4], w[5], w[6], w[7]);
        pf[s][0] = __builtin_bit_cast(short8, u0);
        pf[s][1] = __builtin_bit_cast(short8, u1);
      }
      // PV: V fragment shared across both s (halves the V ds_reads)
#pragma unroll
      for (int ks2 = 0; ks2 < 2; ks2++)
#pragma unroll
        for (int n = 0; n < 2; n++) {
          const int vrow = n * 32 + l31;
          const int pc = (kb * 4 + ks2 * 2 + hi) ^ (vrow & 7);
          const short8 vf = *(const short8*)(Vc + vrow * 64 + pc * 8);
          accO[0][n] = __builtin_amdgcn_mfma_f32_32x32x16_bf16(pf[0][ks2], vf,
                                                               accO[0][n], 0, 0, 0);
          accO[1][n] = __builtin_amdgcn_mfma_f32_32x32x16_bf16(pf[1][ks2], vf,
                                                               accO[1][n], 0, 0, 0);
        }
    }
    __syncthreads();   // drains vmcnt(0): next tile staged; cur free to overwrite
    cur ^= 1;
  }

  // epilogue: finalize row sums (partner half holds complementary k rows)
  lsum[0] += __shfl_xor(lsum[0], 32, 64);
  lsum[1] += __shfl_xor(lsum[1], 32, 64);
  const float* nw = norm_w + h * HD_;
  const float nw0 = nw[l31], nw1 = nw[32 + l31];
#pragma unroll
  for (int r = 0; r < 16; r++) {
    const int qr = (r & 3) + 8 * (r >> 2) + 4 * hi;   // q row within wave's 32
    const float s1 = __shfl(lsum[0], qr, 64);
    const float s2 = __shfl(lsum[1], qr, 64);
    const float inv1 = 1.0f / s1;
    const float c2 = lam / s2;
    float o0 = accO[0][0][r] * inv1 - accO[1][0][r] * c2;   // d = l31
    float o1 = accO[0][1][r] * inv1 - accO[1][1][r] * c2;   // d = 32 + l31
    float ss = o0 * o0 + o1 * o1;
#pragma unroll
    for (int msk = 1; msk <= 16; msk <<= 1) ss += __shfl_xor(ss, msk, 64);
    const float rsc = (1.0f - LAMBDA_INIT) * rsqrtf(ss * (1.0f / 64.0f) + EPS_);
    float* dst = out_n + ((size_t)(b * H_ + h) * S_ + q0 + wave * 32 + qr) * HD_;
    dst[l31] = o0 * rsc * nw0;
    dst[32 + l31] = o1 * rsc * nw1;
  }
}

// ---------------------------------------------------------------------------
// Reshape out_n [B,H,S,HD] fp32 -> hidden bf16 (reference cat/transpose/view)
// ---------------------------------------------------------------------------
__global__ __launch_bounds__(256) void reshape_out(const float* __restrict__ out_n,
                                                   unsigned short* __restrict__ hidden) {
  __shared__ float tile[64][65];
  const int tid = threadIdx.x;
  const int bi = blockIdx.x;  // B*H*32 = 1024
  const int tb = bi & 31;
  const int h = (bi >> 5) & 15;
  const int b = bi >> 9;
  const int t0 = tb * 64;
  const float* src = out_n + (((size_t)b * H_ + h) * S_ + t0) * HD_;
#pragma unroll
  for (int rr = 0; rr < 16; rr++) {
    int e = tid + rr * 256;
    tile[e >> 6][e & 63] = src[e];
  }
  __syncthreads();
  unsigned short* dst = hidden + (size_t)b * (S_ * E_) + h * S_ + t0;
#pragma unroll
  for (int rr = 0; rr < 16; rr++) {
    int e = tid + rr * 256;
    int d = e >> 6, tt = e & 63;
    dst[(size_t)d * (H_ * S_) + tt] = f2bf(tile[tt][d]);
  }
}

// ---------------------------------------------------------------------------
extern "C" void kernel_launch(void* const* d_in, const int* in_sizes, int n_in,
                              void* d_out, int out_size, void* d_ws, size_t ws_size,
                              hipStream_t stream) {
  const float* x = (const float*)d_in[0];
  const float* w_qkv = (const float*)d_in[1];
  const float* wo = (const float*)d_in[2];
  const float* lq1 = (const float*)d_in[3];
  const float* lq2 = (const float*)d_in[4];
  const float* lk1 = (const float*)d_in[5];
  const float* lk2 = (const float*)d_in[6];
  const float* norm_w = (const float*)d_in[7];
  float* out = (float*)d_out;

  unsigned short* xB = (unsigned short*)d_ws;             // 4096*1024
  unsigned short* WT = xB + (size_t)4096 * 1024;          // 3072*1024 (w_qkv^T)
  unsigned short* woT = WT + (size_t)3072 * 1024;         // 1024*1024
  unsigned short* qkB = woT + (size_t)1024 * 1024;        // 4096*2048
  unsigned short* vTB = qkB + (size_t)4096 * 2048;        // 1024*4096
  unsigned short* hidB = vTB + (size_t)1024 * 4096;       // 4096*1024
  float* out_n = (float*)(hidB + (size_t)4096 * 1024);    // 4 Mi floats

  // 0) bf16 casts / transposes of inputs
  cast_bf16<<<1024, 256, 0, stream>>>(x, xB, 4096 * 1024 / 4);
  transpose_cast<<<dim3(48, 16), 256, 0, stream>>>(w_qkv, WT, 1024, 3072);
  transpose_cast<<<dim3(16, 16), 256, 0, stream>>>(wo, woT, 1024, 1024);

  // 1a) q,k = x @ Wqk      -> qkB bf16 [4096][2048]  (128x128 tile, 512 blocks)
  gemm_bt<true, 128><<<dim3(2048 / 128, 4096 / 128), 256, 0, stream>>>(
      xB, WT, (void*)qkB, 4096, 2048, 1024);
  // 1b) vT = Wv^T @ x^T    -> vTB bf16 [1024][4096]  (128x64 tile: 512 blocks,
  //     2 blocks/CU instead of 1 -- latency hiding for the skinny-M GEMM)
  gemm_bt<true, 64><<<dim3(4096 / 64, 1024 / 128), 256, 0, stream>>>(
      WT + (size_t)2048 * 1024, xB, (void*)vTB, 1024, 4096, 1024);

  // 2) MFMA differential flash attention + RMSNorm (128 q rows / block)
  flash_attn_mfma<<<B_ * H_ * (S_ / 128), 256, 0, stream>>>(qkB, vTB, lq1, lq2, lk1,
                                                            lk2, norm_w, out_n);
  // 3) reshape per reference's cat/transpose/view -> bf16
  reshape_out<<<B_ * H_ * (S_ / 64), 256, 0, stream>>>(out_n, hidB);
  // 4) out = hidden @ wo (fp32 out)  (128x64 tile: 512 blocks, 2 blocks/CU)
  gemm_bt<false, 64><<<dim3(1024 / 64, 4096 / 128), 256, 0, stream>>>(
      hidB, woT, (void*)out, 4096, 1024, 1024);
}

// Round 7
// 236.434 us; speedup vs baseline: 1.2010x; 1.0651x over previous
//
#include <hip/hip_runtime.h>
#include <math.h>

#define B_ 2
#define S_ 2048
#define E_ 1024
#define H_ 16
#define HD_ 64
#define LAMBDA_INIT 0.8f
#define EPS_ 1e-6f

typedef __attribute__((ext_vector_type(8))) short short8;   // 8 bf16 (4 VGPRs)
typedef __attribute__((ext_vector_type(4))) float floatx4;  // MFMA C/D 16x16
typedef __attribute__((ext_vector_type(16))) float floatx16; // MFMA C/D 32x32

__device__ __forceinline__ unsigned short f2bf(float f) {
  unsigned u = __float_as_uint(f);
  u += 0x7FFFu + ((u >> 16) & 1u);   // RNE
  return (unsigned short)(u >> 16);
}

__device__ __forceinline__ void gl_lds16(const void* g, void* l) {
  __builtin_amdgcn_global_load_lds((const __attribute__((address_space(1))) void*)g,
                                   (__attribute__((address_space(3))) void*)l,
                                   16, 0, 0);
}

// ---------------------------------------------------------------------------
// cast fp32 -> bf16, contiguous
// ---------------------------------------------------------------------------
__global__ __launch_bounds__(256) void cast_bf16(const float* __restrict__ in,
                                                 unsigned short* __restrict__ out,
                                                 int n4) {
  for (int i = blockIdx.x * 256 + threadIdx.x; i < n4; i += gridDim.x * 256) {
    float4 v = ((const float4*)in)[i];
    ushort4 w;
    w.x = f2bf(v.x); w.y = f2bf(v.y); w.z = f2bf(v.z); w.w = f2bf(v.w);
    ((ushort4*)out)[i] = w;
  }
}

// ---------------------------------------------------------------------------
// transpose + cast: in fp32 [R][C] -> out bf16 [C][R]
// ---------------------------------------------------------------------------
__global__ __launch_bounds__(256) void transpose_cast(const float* __restrict__ in,
                                                      unsigned short* __restrict__ out,
                                                      int R, int C) {
  __shared__ float tile[64][65];
  const int tid = threadIdx.x;
  const int c0 = blockIdx.x * 64;
  const int r0 = blockIdx.y * 64;
#pragma unroll
  for (int it = 0; it < 16; it++) {
    int e = tid + it * 256;
    int rr = e >> 6, cc = e & 63;
    tile[rr][cc] = in[(size_t)(r0 + rr) * C + c0 + cc];
  }
  __syncthreads();
#pragma unroll
  for (int it = 0; it < 16; it++) {
    int e = tid + it * 256;
    int rr = e >> 6, cc = e & 63;
    out[(size_t)(c0 + rr) * R + r0 + cc] = f2bf(tile[cc][rr]);
  }
}

// ---------------------------------------------------------------------------
// bf16 MFMA GEMM: C[M][N] = A[M][K] @ B[K][N], B given TRANSPOSED as Bt[N][K].
// Tile 128 x BNT (BNT = 128 or 64), BK=64, 256 thr (4 waves, 2x2 of
// 64 x BNT/2), global_load_lds w=16, XOR chunk swizzle (c_phys = c_log^(r&7))
// -> ds_read_b128 frags <=2-way. BNT=64 doubles block count for skinny-N
// GEMMs (1 -> 2 blocks/CU): K-accumulation order unchanged -> bitwise-same C.
// ---------------------------------------------------------------------------
template <bool BF16OUT, int BNT>
__global__ __launch_bounds__(256, BNT == 64 ? 2 : 1) void gemm_bt(
    const unsigned short* __restrict__ A, const unsigned short* __restrict__ Bt,
    void* __restrict__ C, int M, int N, int K) {
  __shared__ __align__(16) unsigned short As[128 * 64];
  __shared__ __align__(16) unsigned short Bs[BNT * 64];
  const int tid = threadIdx.x;
  const int wave = tid >> 6, lane = tid & 63;
  const int lane15 = lane & 15, quad = lane >> 4;
  const int m0 = blockIdx.y * 128;
  const int n0 = blockIdx.x * BNT;
  const int wm = (wave & 1) * 64, wn = (wave >> 1) * (BNT / 2);
  const int NI = BNT / 32;   // n-fragments per wave

  floatx4 acc[4][NI];
#pragma unroll
  for (int mi = 0; mi < 4; mi++)
#pragma unroll
    for (int ni = 0; ni < NI; ni++) acc[mi][ni] = (floatx4)0.0f;

  const int rsA = wave * 32 + (lane >> 3);        // A staging row base (+j*8)
  const int rsB = wave * (BNT / 4) + (lane >> 3); // B staging row base (+j*8)
  const int cph = lane & 7;                       // physical chunk this lane fills

  for (int k0 = 0; k0 < K; k0 += 64) {
    __syncthreads();   // prior iter's fragment reads done
#pragma unroll
    for (int j = 0; j < 4; j++) {
      int r = rsA + j * 8;
      int cl = cph ^ (r & 7);
      gl_lds16(A + (size_t)(m0 + r) * K + k0 + cl * 8, &As[(wave * 32 + j * 8) * 64]);
    }
#pragma unroll
    for (int j = 0; j < BNT / 32; j++) {
      int r = rsB + j * 8;
      int cl = cph ^ (r & 7);
      gl_lds16(Bt + (size_t)(n0 + r) * K + k0 + cl * 8,
               &Bs[(wave * (BNT / 4) + j * 8) * 64]);
    }
    __syncthreads();   // drains vmcnt(0): staged data visible

#pragma unroll
    for (int ks = 0; ks < 2; ks++) {
      short8 af[4], bf[NI];
#pragma unroll
      for (int mi = 0; mi < 4; mi++) {
        int r = wm + mi * 16 + lane15;
        int phys = (ks * 4 + quad) ^ (r & 7);
        af[mi] = *(const short8*)(&As[r * 64 + phys * 8]);
      }
#pragma unroll
      for (int ni = 0; ni < NI; ni++) {
        int r = wn + ni * 16 + lane15;
        int phys = (ks * 4 + quad) ^ (r & 7);
        bf[ni] = *(const short8*)(&Bs[r * 64 + phys * 8]);
      }
#pragma unroll
      for (int mi = 0; mi < 4; mi++)
#pragma unroll
        for (int ni = 0; ni < NI; ni++)
          acc[mi][ni] = __builtin_amdgcn_mfma_f32_16x16x32_bf16(af[mi], bf[ni],
                                                                acc[mi][ni], 0, 0, 0);
    }
  }

#pragma unroll
  for (int mi = 0; mi < 4; mi++)
#pragma unroll
    for (int ni = 0; ni < NI; ni++)
#pragma unroll
      for (int reg = 0; reg < 4; reg++) {
        int row = m0 + wm + mi * 16 + quad * 4 + reg;
        int col = n0 + wn + ni * 16 + lane15;
        float v = acc[mi][ni][reg];
        if (BF16OUT)
          ((unsigned short*)C)[(size_t)row * N + col] = f2bf(v);
        else
          ((float*)C)[(size_t)row * N + col] = v;
      }
}

// ---------------------------------------------------------------------------
// MFMA flash differential attention, 32x32x16 swapped-QK^T, SPLIT-S waves.
// Block = 128 q rows, 512 threads, 8 waves = (qsub 0..3) x (sw 0..1); each
// wave computes ONE softmax branch (sw) for its 32 q rows. Inner-loop math
// and formulas are byte-copied from the verified R2 kernel with s := sw.
// Rationale (R6 counters): VALUBusy 62% at 1.5 waves/SIMD -> VALU-stall-bound;
// doubling waves/SIMD fills the stalls without changing total work.
// Epilogue exchange is INDEX-MATCHED: partner waves (same qsub) share
// identical (lane, r, n) coordinates, so sw=1 stores accO[n][r] at
// [qsub][(n*16+r)][lane] (lane-contiguous, conflict-free) in the dead K/V
// LDS and sw=0 reads the same flat index. No coordinate remapping anywhere.
// ---------------------------------------------------------------------------
__global__ __launch_bounds__(512, 4) void flash_attn_mfma(
    const unsigned short* __restrict__ qkB, const unsigned short* __restrict__ vTB,
    const float* __restrict__ lq1, const float* __restrict__ lq2,
    const float* __restrict__ lk1, const float* __restrict__ lk2,
    const float* __restrict__ norm_w, float* __restrict__ out_n) {
  __shared__ __align__(16) unsigned short KV[2][2][64 * 64];   // [buf][0=K,1=V]
  __shared__ float Lex[4][64];                                 // sw=1 lsum

  const int tid = threadIdx.x;
  const int wave = tid >> 6, lane = tid & 63;
  const int l31 = lane & 31, hi = lane >> 5;
  const int qsub = wave >> 1, sw = wave & 1;

  // bijective XCD swizzle: the 16 q-tiles sharing one (b,h)'s K/V land on one XCD
  const int bid = (blockIdx.x & 7) * 64 + (blockIdx.x >> 3);   // 512 blocks
  const int qt = bid & 15;
  const int h = (bid >> 4) & 15;
  const int b = bid >> 8;
  const int q0 = qt * 128;

  float a1 = 0.f, a2 = 0.f;
  for (int d = 0; d < HD_; d++) {
    a1 += lq1[d] * lk1[d];
    a2 += lq2[d] * lk2[d];
  }
  const float lam = __expf(a1) - __expf(a2) + LAMBDA_INIT;

  // Q fragments for MY branch: Q[q = q0+qsub*32+l31][h*64 + sw*32 + cs*16 + hi*8]
  short8 qf[2];
  {
    const unsigned short* qrow =
        qkB + (size_t)(b * S_ + q0 + qsub * 32 + l31) * 2048 + h * 64 + sw * 32;
#pragma unroll
    for (int cs = 0; cs < 2; cs++)
      qf[cs] = *(const short8*)(qrow + cs * 16 + hi * 8);
  }

  floatx16 accO[2];
#pragma unroll
  for (int n = 0; n < 2; n++) accO[n] = (floatx16)0.0f;
  float lsum = 0.f;
  const floatx16 zero16 = (floatx16)0.0f;

  const int srow = tid >> 3;   // 512 threads cover all 64 rows in one round
  const int scol = tid & 7;    // physical 16B chunk this lane fills
  const size_t kgbase = (size_t)(b * S_) * 2048 + 1024 + h * 64;
  const size_t vgbase = (size_t)h * 64 * 4096 + b * 2048;

  // stage tile t into buffer buf: 1 K + 1 V gl_lds per thread
#define STAGE(t_, buf_)                                                        \
  {                                                                            \
    const size_t kg_ = kgbase + (size_t)(t_) * 64 * 2048;                      \
    const size_t vg_ = vgbase + (size_t)(t_) * 64;                             \
    const int cl_ = scol ^ (srow & 7);                                         \
    gl_lds16(qkB + kg_ + (size_t)srow * 2048 + cl_ * 8,                        \
             &KV[buf_][0][(wave * 8) * 64]);                                   \
    gl_lds16(vTB + vg_ + (size_t)srow * 4096 + cl_ * 8,                        \
             &KV[buf_][1][(wave * 8) * 64]);                                   \
  }

  // prologue: stage tile 0 into buffer 0
  STAGE(0, 0);
  __syncthreads();

  int cur = 0;
  for (int t = 0; t < S_ / 64; t++) {
    if (t < S_ / 64 - 1) STAGE(t + 1, cur ^ 1);   // async prefetch
    const unsigned short* Kc = &KV[cur][0][0];
    const unsigned short* Vc = &KV[cur][1][0];

#pragma unroll
    for (int kb = 0; kb < 2; kb++) {
      const int krow = kb * 32 + l31;
      const int kx = krow & 7;
      floatx16 accS = zero16;
#pragma unroll
      for (int cs = 0; cs < 2; cs++) {
        const int pc = (sw * 4 + cs * 2 + hi) ^ kx;
        const short8 kf = *(const short8*)(Kc + krow * 64 + pc * 8);
        accS = __builtin_amdgcn_mfma_f32_32x32x16_bf16(kf, qf[cs], accS, 0, 0, 0);
      }
      // accS: q = l31 (col), k row = (reg&3) + 8*(reg>>2) + 4*hi
      unsigned w[8];
      float ls = 0.f;
#pragma unroll
      for (int i = 0; i < 8; i++) {
        float p0 = __expf(accS[2 * i] * 0.125f);
        float p1 = __expf(accS[2 * i + 1] * 0.125f);
        ls += p0 + p1;
        asm("v_cvt_pk_bf16_f32 %0, %1, %2" : "=v"(w[i]) : "v"(p0), "v"(p1));
      }
      lsum += ls;
      // dst.hi <-> src.lo: dst = low k-quad pack, src = high k-quad pack
      asm volatile("v_permlane32_swap_b32 %0, %1" : "+v"(w[0]), "+v"(w[2]));
      asm volatile("v_permlane32_swap_b32 %0, %1" : "+v"(w[1]), "+v"(w[3]));
      asm volatile("v_permlane32_swap_b32 %0, %1" : "+v"(w[4]), "+v"(w[6]));
      asm volatile("v_permlane32_swap_b32 %0, %1" : "+v"(w[5]), "+v"(w[7]));
      uint4 u0 = make_uint4(w[0], w[1], w[2], w[3]);
      uint4 u1 = make_uint4(w[4], w[5], w[6], w[7]);
      short8 pf0 = __builtin_bit_cast(short8, u0);
      short8 pf1 = __builtin_bit_cast(short8, u1);
      // PV for MY branch over this kb
#pragma unroll
      for (int ks2 = 0; ks2 < 2; ks2++) {
        const short8 pa = ks2 ? pf1 : pf0;
#pragma unroll
        for (int n = 0; n < 2; n++) {
          const int vrow = n * 32 + l31;
          const int pc = (kb * 4 + ks2 * 2 + hi) ^ (vrow & 7);
          const short8 vf = *(const short8*)(Vc + vrow * 64 + pc * 8);
          accO[n] = __builtin_amdgcn_mfma_f32_32x32x16_bf16(pa, vf, accO[n], 0, 0, 0);
        }
      }
    }
    __syncthreads();   // drains vmcnt(0): next tile staged; cur free to overwrite
    cur ^= 1;
  }
#undef STAGE

  // finalize row sums (partner lane-half holds complementary k rows)
  lsum += __shfl_xor(lsum, 32, 64);

  // ---- index-matched exchange: sw=1 pushes partials, sw=0 combines ----
  float* LF = (float*)&KV[0][0][0];   // 8192 floats = the dead K/V buffers
  if (sw == 1) {
    Lex[qsub][lane] = lsum;
#pragma unroll
    for (int n = 0; n < 2; n++)
#pragma unroll
      for (int r = 0; r < 16; r++)
        LF[qsub * 2048 + (n * 16 + r) * 64 + lane] = accO[n][r];
  }
  __syncthreads();

  if (sw == 0) {
    const float ls2v = Lex[qsub][lane];
    const float* nw = norm_w + h * HD_;
    const float nw0 = nw[l31], nw1 = nw[32 + l31];
#pragma unroll
    for (int r = 0; r < 16; r++) {
      const int qr = (r & 3) + 8 * (r >> 2) + 4 * hi;   // q row within wave's 32
      const float s1 = __shfl(lsum, qr, 64);
      const float s2 = __shfl(ls2v, qr, 64);
      const float inv1 = 1.0f / s1;
      const float c2 = lam / s2;
      const float b0 = LF[qsub * 2048 + (0 * 16 + r) * 64 + lane];
      const float b1 = LF[qsub * 2048 + (1 * 16 + r) * 64 + lane];
      float o0 = accO[0][r] * inv1 - b0 * c2;   // d = l31
      float o1 = accO[1][r] * inv1 - b1 * c2;   // d = 32 + l31
      float ss = o0 * o0 + o1 * o1;
#pragma unroll
      for (int msk = 1; msk <= 16; msk <<= 1) ss += __shfl_xor(ss, msk, 64);
      const float rsc = (1.0f - LAMBDA_INIT) * rsqrtf(ss * (1.0f / 64.0f) + EPS_);
      float* dst = out_n + ((size_t)(b * H_ + h) * S_ + q0 + qsub * 32 + qr) * HD_;
      dst[l31] = o0 * rsc * nw0;
      dst[32 + l31] = o1 * rsc * nw1;
    }
  }
}

// ---------------------------------------------------------------------------
// Reshape out_n [B,H,S,HD] fp32 -> hidden bf16 (reference cat/transpose/view)
// ---------------------------------------------------------------------------
__global__ __launch_bounds__(256) void reshape_out(const float* __restrict__ out_n,
                                                   unsigned short* __restrict__ hidden) {
  __shared__ float tile[64][65];
  const int tid = threadIdx.x;
  const int bi = blockIdx.x;  // B*H*32 = 1024
  const int tb = bi & 31;
  const int h = (bi >> 5) & 15;
  const int b = bi >> 9;
  const int t0 = tb * 64;
  const float* src = out_n + (((size_t)b * H_ + h) * S_ + t0) * HD_;
#pragma unroll
  for (int rr = 0; rr < 16; rr++) {
    int e = tid + rr * 256;
    tile[e >> 6][e & 63] = src[e];
  }
  __syncthreads();
  unsigned short* dst = hidden + (size_t)b * (S_ * E_) + h * S_ + t0;
#pragma unroll
  for (int rr = 0; rr < 16; rr++) {
    int e = tid + rr * 256;
    int d = e >> 6, tt = e & 63;
    dst[(size_t)d * (H_ * S_) + tt] = f2bf(tile[tt][d]);
  }
}

// ---------------------------------------------------------------------------
extern "C" void kernel_launch(void* const* d_in, const int* in_sizes, int n_in,
                              void* d_out, int out_size, void* d_ws, size_t ws_size,
                              hipStream_t stream) {
  const float* x = (const float*)d_in[0];
  const float* w_qkv = (const float*)d_in[1];
  const float* wo = (const float*)d_in[2];
  const float* lq1 = (const float*)d_in[3];
  const float* lq2 = (const float*)d_in[4];
  const float* lk1 = (const float*)d_in[5];
  const float* lk2 = (const float*)d_in[6];
  const float* norm_w = (const float*)d_in[7];
  float* out = (float*)d_out;

  unsigned short* xB = (unsigned short*)d_ws;             // 4096*1024
  unsigned short* WT = xB + (size_t)4096 * 1024;          // 3072*1024 (w_qkv^T)
  unsigned short* woT = WT + (size_t)3072 * 1024;         // 1024*1024
  unsigned short* qkB = woT + (size_t)1024 * 1024;        // 4096*2048
  unsigned short* vTB = qkB + (size_t)4096 * 2048;        // 1024*4096
  unsigned short* hidB = vTB + (size_t)1024 * 4096;       // 4096*1024
  float* out_n = (float*)(hidB + (size_t)4096 * 1024);    // 4 Mi floats

  // 0) bf16 casts / transposes of inputs
  cast_bf16<<<1024, 256, 0, stream>>>(x, xB, 4096 * 1024 / 4);
  transpose_cast<<<dim3(48, 16), 256, 0, stream>>>(w_qkv, WT, 1024, 3072);
  transpose_cast<<<dim3(16, 16), 256, 0, stream>>>(wo, woT, 1024, 1024);

  // 1a) q,k = x @ Wqk      -> qkB bf16 [4096][2048]  (128x128 tile, 512 blocks)
  gemm_bt<true, 128><<<dim3(2048 / 128, 4096 / 128), 256, 0, stream>>>(
      xB, WT, (void*)qkB, 4096, 2048, 1024);
  // 1b) vT = Wv^T @ x^T    -> vTB bf16 [1024][4096]  (128x64 tile: 512 blocks)
  gemm_bt<true, 64><<<dim3(4096 / 64, 1024 / 128), 256, 0, stream>>>(
      WT + (size_t)2048 * 1024, xB, (void*)vTB, 1024, 4096, 1024);

  // 2) MFMA differential flash attention + RMSNorm (128 q rows, 8 waves, split-s)
  flash_attn_mfma<<<B_ * H_ * (S_ / 128), 512, 0, stream>>>(qkB, vTB, lq1, lq2, lk1,
                                                            lk2, norm_w, out_n);
  // 3) reshape per reference's cat/transpose/view -> bf16
  reshape_out<<<B_ * H_ * (S_ / 64), 256, 0, stream>>>(out_n, hidB);
  // 4) out = hidden @ wo (fp32 out)  (128x64 tile: 512 blocks, 2 blocks/CU)
  gemm_bt<false, 64><<<dim3(1024 / 64, 4096 / 128), 256, 0, stream>>>(
      hidB, woT, (void*)out, 4096, 1024, 1024);
}

// Round 9
// 227.805 us; speedup vs baseline: 1.2465x; 1.0379x over previous
//
#include <hip/hip_runtime.h>
#include <math.h>

#define B_ 2
#define S_ 2048
#define E_ 1024
#define H_ 16
#define HD_ 64
#define LAMBDA_INIT 0.8f
#define EPS_ 1e-6f

typedef __attribute__((ext_vector_type(8))) short short8;   // 8 bf16 (4 VGPRs)
typedef __attribute__((ext_vector_type(8))) unsigned short ushort8v;
typedef __attribute__((ext_vector_type(4))) float floatx4;  // MFMA C/D 16x16
typedef __attribute__((ext_vector_type(16))) float floatx16; // MFMA C/D 32x32

__device__ __forceinline__ unsigned short f2bf(float f) {
  unsigned u = __float_as_uint(f);
  u += 0x7FFFu + ((u >> 16) & 1u);   // RNE
  return (unsigned short)(u >> 16);
}

__device__ __forceinline__ void gl_lds16(const void* g, void* l) {
  __builtin_amdgcn_global_load_lds((const __attribute__((address_space(1))) void*)g,
                                   (__attribute__((address_space(3))) void*)l,
                                   16, 0, 0);
}

// ---------------------------------------------------------------------------
// prep: fused {cast x -> bf16} + {transpose_cast w_qkv} + {transpose_cast wo}.
// Branch on blockIdx (block-uniform); per-branch code identical to the
// verified cast_bf16 / transpose_cast kernels -> bitwise-identical outputs.
// grid 2048: [0,1024) cast, [1024,1792) w_qkv 48x16, [1792,2048) wo 16x16.
// ---------------------------------------------------------------------------
__global__ __launch_bounds__(256) void prep(const float* __restrict__ x,
                                            const float* __restrict__ w_qkv,
                                            const float* __restrict__ wo,
                                            unsigned short* __restrict__ xB,
                                            unsigned short* __restrict__ WT,
                                            unsigned short* __restrict__ woT) {
  __shared__ float tile[64][65];
  const int tid = threadIdx.x;
  const int bid = blockIdx.x;
  if (bid < 1024) {
    const int n4 = 4096 * 1024 / 4;
    for (int i = bid * 256 + tid; i < n4; i += 1024 * 256) {
      float4 v = ((const float4*)x)[i];
      ushort4 w;
      w.x = f2bf(v.x); w.y = f2bf(v.y); w.z = f2bf(v.z); w.w = f2bf(v.w);
      ((ushort4*)xB)[i] = w;
    }
    return;
  }
  const float* in;
  unsigned short* out;
  int R, C, bx, by;
  if (bid < 1792) {
    in = w_qkv; out = WT; R = 1024; C = 3072;
    int t = bid - 1024; bx = t % 48; by = t / 48;
  } else {
    in = wo; out = woT; R = 1024; C = 1024;
    int t = bid - 1792; bx = t % 16; by = t / 16;
  }
  const int c0 = bx * 64;
  const int r0 = by * 64;
#pragma unroll
  for (int it = 0; it < 16; it++) {
    int e = tid + it * 256;
    int rr = e >> 6, cc = e & 63;
    tile[rr][cc] = in[(size_t)(r0 + rr) * C + c0 + cc];
  }
  __syncthreads();
#pragma unroll
  for (int it = 0; it < 16; it++) {
    int e = tid + it * 256;
    int rr = e >> 6, cc = e & 63;
    out[(size_t)(c0 + rr) * R + r0 + cc] = f2bf(tile[cc][rr]);
  }
}

// ---------------------------------------------------------------------------
// bf16 MFMA GEMM: C[M][N] = A[M][K] @ B[K][N], B given TRANSPOSED as Bt[N][K].
// Tile 128 x BNT (BNT = 128 or 64), BK=64, 256 thr (4 waves, 2x2 of
// 64 x BNT/2), global_load_lds w=16, XOR chunk swizzle (c_phys = c_log^(r&7))
// -> ds_read_b128 frags <=2-way. BNT=64 doubles block count for skinny-N
// GEMMs (1 -> 2 blocks/CU): K-accumulation order unchanged -> bitwise-same C.
// ---------------------------------------------------------------------------
template <bool BF16OUT, int BNT>
__global__ __launch_bounds__(256, BNT == 64 ? 2 : 1) void gemm_bt(
    const unsigned short* __restrict__ A, const unsigned short* __restrict__ Bt,
    void* __restrict__ C, int M, int N, int K) {
  __shared__ __align__(16) unsigned short As[128 * 64];
  __shared__ __align__(16) unsigned short Bs[BNT * 64];
  const int tid = threadIdx.x;
  const int wave = tid >> 6, lane = tid & 63;
  const int lane15 = lane & 15, quad = lane >> 4;
  const int m0 = blockIdx.y * 128;
  const int n0 = blockIdx.x * BNT;
  const int wm = (wave & 1) * 64, wn = (wave >> 1) * (BNT / 2);
  const int NI = BNT / 32;   // n-fragments per wave

  floatx4 acc[4][NI];
#pragma unroll
  for (int mi = 0; mi < 4; mi++)
#pragma unroll
    for (int ni = 0; ni < NI; ni++) acc[mi][ni] = (floatx4)0.0f;

  const int rsA = wave * 32 + (lane >> 3);        // A staging row base (+j*8)
  const int rsB = wave * (BNT / 4) + (lane >> 3); // B staging row base (+j*8)
  const int cph = lane & 7;                       // physical chunk this lane fills

  for (int k0 = 0; k0 < K; k0 += 64) {
    __syncthreads();   // prior iter's fragment reads done
#pragma unroll
    for (int j = 0; j < 4; j++) {
      int r = rsA + j * 8;
      int cl = cph ^ (r & 7);
      gl_lds16(A + (size_t)(m0 + r) * K + k0 + cl * 8, &As[(wave * 32 + j * 8) * 64]);
    }
#pragma unroll
    for (int j = 0; j < BNT / 32; j++) {
      int r = rsB + j * 8;
      int cl = cph ^ (r & 7);
      gl_lds16(Bt + (size_t)(n0 + r) * K + k0 + cl * 8,
               &Bs[(wave * (BNT / 4) + j * 8) * 64]);
    }
    __syncthreads();   // drains vmcnt(0): staged data visible

#pragma unroll
    for (int ks = 0; ks < 2; ks++) {
      short8 af[4], bf[NI];
#pragma unroll
      for (int mi = 0; mi < 4; mi++) {
        int r = wm + mi * 16 + lane15;
        int phys = (ks * 4 + quad) ^ (r & 7);
        af[mi] = *(const short8*)(&As[r * 64 + phys * 8]);
      }
#pragma unroll
      for (int ni = 0; ni < NI; ni++) {
        int r = wn + ni * 16 + lane15;
        int phys = (ks * 4 + quad) ^ (r & 7);
        bf[ni] = *(const short8*)(&Bs[r * 64 + phys * 8]);
      }
#pragma unroll
      for (int mi = 0; mi < 4; mi++)
#pragma unroll
        for (int ni = 0; ni < NI; ni++)
          acc[mi][ni] = __builtin_amdgcn_mfma_f32_16x16x32_bf16(af[mi], bf[ni],
                                                                acc[mi][ni], 0, 0, 0);
    }
  }

#pragma unroll
  for (int mi = 0; mi < 4; mi++)
#pragma unroll
    for (int ni = 0; ni < NI; ni++)
#pragma unroll
      for (int reg = 0; reg < 4; reg++) {
        int row = m0 + wm + mi * 16 + quad * 4 + reg;
        int col = n0 + wn + ni * 16 + lane15;
        float v = acc[mi][ni][reg];
        if (BF16OUT)
          ((unsigned short*)C)[(size_t)row * N + col] = f2bf(v);
        else
          ((float*)C)[(size_t)row * N + col] = v;
      }
}

// ---------------------------------------------------------------------------
// MFMA flash differential attention, 32x32x16 swapped-QK^T, SPLIT-S waves.
// [Main loop + exchange byte-identical to verified R7.] Block = 128 q rows,
// 512 threads, 8 waves = (qsub 0..3) x (sw 0..1). NEW (epilogue only): the
// reshape_out kernel is fused here -- sw=0 waves write o*rsc*nw into a padded
// LDS tile LF2[64][130] (fp32, exact), then after a barrier all 512 threads
// do the d-major coalesced bf16 store into hidden with reshape_out's exact
// index map: hidden[b*S*E + d*H*S + h*S + q]. Bitwise-identical output; kills
// the reshape kernel, its launch gap, and 32 MB of out_n round-trip traffic.
// ---------------------------------------------------------------------------
__global__ __launch_bounds__(512, 4) void flash_attn_mfma(
    const unsigned short* __restrict__ qkB, const unsigned short* __restrict__ vTB,
    const float* __restrict__ lq1, const float* __restrict__ lq2,
    const float* __restrict__ lk1, const float* __restrict__ lk2,
    const float* __restrict__ norm_w, unsigned short* __restrict__ hid) {
  __shared__ __align__(16) unsigned short KV[2][2][64 * 64];   // [buf][0=K,1=V]
  __shared__ float Lex[4][64];                                 // sw=1 lsum
  __shared__ float LF2[64][130];                               // [d][q] out tile

  const int tid = threadIdx.x;
  const int wave = tid >> 6, lane = tid & 63;
  const int l31 = lane & 31, hi = lane >> 5;
  const int qsub = wave >> 1, sw = wave & 1;

  // bijective XCD swizzle: the 16 q-tiles sharing one (b,h)'s K/V land on one XCD
  const int bid = (blockIdx.x & 7) * 64 + (blockIdx.x >> 3);   // 512 blocks
  const int qt = bid & 15;
  const int h = (bid >> 4) & 15;
  const int b = bid >> 8;
  const int q0 = qt * 128;

  float a1 = 0.f, a2 = 0.f;
  for (int d = 0; d < HD_; d++) {
    a1 += lq1[d] * lk1[d];
    a2 += lq2[d] * lk2[d];
  }
  const float lam = __expf(a1) - __expf(a2) + LAMBDA_INIT;

  // Q fragments for MY branch: Q[q = q0+qsub*32+l31][h*64 + sw*32 + cs*16 + hi*8]
  short8 qf[2];
  {
    const unsigned short* qrow =
        qkB + (size_t)(b * S_ + q0 + qsub * 32 + l31) * 2048 + h * 64 + sw * 32;
#pragma unroll
    for (int cs = 0; cs < 2; cs++)
      qf[cs] = *(const short8*)(qrow + cs * 16 + hi * 8);
  }

  floatx16 accO[2];
#pragma unroll
  for (int n = 0; n < 2; n++) accO[n] = (floatx16)0.0f;
  float lsum = 0.f;
  const floatx16 zero16 = (floatx16)0.0f;

  const int srow = tid >> 3;   // 512 threads cover all 64 rows in one round
  const int scol = tid & 7;    // physical 16B chunk this lane fills
  const size_t kgbase = (size_t)(b * S_) * 2048 + 1024 + h * 64;
  const size_t vgbase = (size_t)h * 64 * 4096 + b * 2048;

  // stage tile t into buffer buf: 1 K + 1 V gl_lds per thread
#define STAGE(t_, buf_)                                                        \
  {                                                                            \
    const size_t kg_ = kgbase + (size_t)(t_) * 64 * 2048;                      \
    const size_t vg_ = vgbase + (size_t)(t_) * 64;                             \
    const int cl_ = scol ^ (srow & 7);                                         \
    gl_lds16(qkB + kg_ + (size_t)srow * 2048 + cl_ * 8,                        \
             &KV[buf_][0][(wave * 8) * 64]);                                   \
    gl_lds16(vTB + vg_ + (size_t)srow * 4096 + cl_ * 8,                        \
             &KV[buf_][1][(wave * 8) * 64]);                                   \
  }

  // prologue: stage tile 0 into buffer 0
  STAGE(0, 0);
  __syncthreads();

  int cur = 0;
  for (int t = 0; t < S_ / 64; t++) {
    if (t < S_ / 64 - 1) STAGE(t + 1, cur ^ 1);   // async prefetch
    const unsigned short* Kc = &KV[cur][0][0];
    const unsigned short* Vc = &KV[cur][1][0];

#pragma unroll
    for (int kb = 0; kb < 2; kb++) {
      const int krow = kb * 32 + l31;
      const int kx = krow & 7;
      floatx16 accS = zero16;
#pragma unroll
      for (int cs = 0; cs < 2; cs++) {
        const int pc = (sw * 4 + cs * 2 + hi) ^ kx;
        const short8 kf = *(const short8*)(Kc + krow * 64 + pc * 8);
        accS = __builtin_amdgcn_mfma_f32_32x32x16_bf16(kf, qf[cs], accS, 0, 0, 0);
      }
      // accS: q = l31 (col), k row = (reg&3) + 8*(reg>>2) + 4*hi
      unsigned w[8];
      float ls = 0.f;
#pragma unroll
      for (int i = 0; i < 8; i++) {
        float p0 = __expf(accS[2 * i] * 0.125f);
        float p1 = __expf(accS[2 * i + 1] * 0.125f);
        ls += p0 + p1;
        asm("v_cvt_pk_bf16_f32 %0, %1, %2" : "=v"(w[i]) : "v"(p0), "v"(p1));
      }
      lsum += ls;
      // dst.hi <-> src.lo: dst = low k-quad pack, src = high k-quad pack
      asm volatile("v_permlane32_swap_b32 %0, %1" : "+v"(w[0]), "+v"(w[2]));
      asm volatile("v_permlane32_swap_b32 %0, %1" : "+v"(w[1]), "+v"(w[3]));
      asm volatile("v_permlane32_swap_b32 %0, %1" : "+v"(w[4]), "+v"(w[6]));
      asm volatile("v_permlane32_swap_b32 %0, %1" : "+v"(w[5]), "+v"(w[7]));
      uint4 u0 = make_uint4(w[0], w[1], w[2], w[3]);
      uint4 u1 = make_uint4(w[4], w[5], w[6], w[7]);
      short8 pf0 = __builtin_bit_cast(short8, u0);
      short8 pf1 = __builtin_bit_cast(short8, u1);
      // PV for MY branch over this kb
#pragma unroll
      for (int ks2 = 0; ks2 < 2; ks2++) {
        const short8 pa = ks2 ? pf1 : pf0;
#pragma unroll
        for (int n = 0; n < 2; n++) {
          const int vrow = n * 32 + l31;
          const int pc = (kb * 4 + ks2 * 2 + hi) ^ (vrow & 7);
          const short8 vf = *(const short8*)(Vc + vrow * 64 + pc * 8);
          accO[n] = __builtin_amdgcn_mfma_f32_32x32x16_bf16(pa, vf, accO[n], 0, 0, 0);
        }
      }
    }
    __syncthreads();   // drains vmcnt(0): next tile staged; cur free to overwrite
    cur ^= 1;
  }
#undef STAGE

  // finalize row sums (partner lane-half holds complementary k rows)
  lsum += __shfl_xor(lsum, 32, 64);

  // ---- index-matched exchange: sw=1 pushes partials, sw=0 combines ----
  float* LF = (float*)&KV[0][0][0];   // 8192 floats = the dead K/V buffers
  if (sw == 1) {
    Lex[qsub][lane] = lsum;
#pragma unroll
    for (int n = 0; n < 2; n++)
#pragma unroll
      for (int r = 0; r < 16; r++)
        LF[qsub * 2048 + (n * 16 + r) * 64 + lane] = accO[n][r];
  }
  __syncthreads();

  if (sw == 0) {
    const float ls2v = Lex[qsub][lane];
    const float* nw = norm_w + h * HD_;
    const float nw0 = nw[l31], nw1 = nw[32 + l31];
#pragma unroll
    for (int r = 0; r < 16; r++) {
      const int qr = (r & 3) + 8 * (r >> 2) + 4 * hi;   // q row within wave's 32
      const float s1 = __shfl(lsum, qr, 64);
      const float s2 = __shfl(ls2v, qr, 64);
      const float inv1 = 1.0f / s1;
      const float c2 = lam / s2;
      const float b0 = LF[qsub * 2048 + (0 * 16 + r) * 64 + lane];
      const float b1 = LF[qsub * 2048 + (1 * 16 + r) * 64 + lane];
      float o0 = accO[0][r] * inv1 - b0 * c2;   // d = l31
      float o1 = accO[1][r] * inv1 - b1 * c2;   // d = 32 + l31
      float ss = o0 * o0 + o1 * o1;
#pragma unroll
      for (int msk = 1; msk <= 16; msk <<= 1) ss += __shfl_xor(ss, msk, 64);
      const float rsc = (1.0f - LAMBDA_INIT) * rsqrtf(ss * (1.0f / 64.0f) + EPS_);
      LF2[l31][qsub * 32 + qr] = o0 * rsc * nw0;        // fp32 staging (exact)
      LF2[32 + l31][qsub * 32 + qr] = o1 * rsc * nw1;
    }
  }
  __syncthreads();

  // ---- fused reshape: all 512 threads, d-major coalesced bf16 store ----
  // hidden[b*S*E + d*H*S + h*S + (q0 + qq)] = bf16(LF2[d][qq])
  {
    const int d = tid >> 3, g = tid & 7;
    unsigned short* dst =
        hid + (size_t)b * (S_ * E_) + (size_t)d * (H_ * S_) + h * S_ + q0 + g * 16;
    ushort8v v0, v1;
#pragma unroll
    for (int j = 0; j < 8; j++) {
      v0[j] = f2bf(LF2[d][g * 16 + j]);
      v1[j] = f2bf(LF2[d][g * 16 + 8 + j]);
    }
    *(ushort8v*)(dst) = v0;
    *(ushort8v*)(dst + 8) = v1;
  }
}

// ---------------------------------------------------------------------------
extern "C" void kernel_launch(void* const* d_in, const int* in_sizes, int n_in,
                              void* d_out, int out_size, void* d_ws, size_t ws_size,
                              hipStream_t stream) {
  const float* x = (const float*)d_in[0];
  const float* w_qkv = (const float*)d_in[1];
  const float* wo = (const float*)d_in[2];
  const float* lq1 = (const float*)d_in[3];
  const float* lq2 = (const float*)d_in[4];
  const float* lk1 = (const float*)d_in[5];
  const float* lk2 = (const float*)d_in[6];
  const float* norm_w = (const float*)d_in[7];
  float* out = (float*)d_out;

  unsigned short* xB = (unsigned short*)d_ws;             // 4096*1024
  unsigned short* WT = xB + (size_t)4096 * 1024;          // 3072*1024 (w_qkv^T)
  unsigned short* woT = WT + (size_t)3072 * 1024;         // 1024*1024
  unsigned short* qkB = woT + (size_t)1024 * 1024;        // 4096*2048
  unsigned short* vTB = qkB + (size_t)4096 * 2048;        // 1024*4096
  unsigned short* hidB = vTB + (size_t)1024 * 4096;       // 4096*1024

  // 0) fused bf16 cast + transposes of inputs (one launch)
  prep<<<2048, 256, 0, stream>>>(x, w_qkv, wo, xB, WT, woT);

  // 1a) q,k = x @ Wqk      -> qkB bf16 [4096][2048]  (128x128 tile, 512 blocks)
  gemm_bt<true, 128><<<dim3(2048 / 128, 4096 / 128), 256, 0, stream>>>(
      xB, WT, (void*)qkB, 4096, 2048, 1024);
  // 1b) vT = Wv^T @ x^T    -> vTB bf16 [1024][4096]  (128x64 tile: 512 blocks)
  gemm_bt<true, 64><<<dim3(4096 / 64, 1024 / 128), 256, 0, stream>>>(
      WT + (size_t)2048 * 1024, xB, (void*)vTB, 1024, 4096, 1024);

  // 2) MFMA differential flash attention + RMSNorm + fused reshape -> hidB bf16
  flash_attn_mfma<<<B_ * H_ * (S_ / 128), 512, 0, stream>>>(qkB, vTB, lq1, lq2, lk1,
                                                            lk2, norm_w, hidB);
  // 3) out = hidden @ wo (fp32 out)  (128x64 tile: 512 blocks, 2 blocks/CU)
  gemm_bt<false, 64><<<dim3(1024 / 64, 4096 / 128), 256, 0, stream>>>(
      hidB, woT, (void*)out, 4096, 1024, 1024);
}

// Round 10
// 225.956 us; speedup vs baseline: 1.2567x; 1.0082x over previous
//
#include <hip/hip_runtime.h>
#include <math.h>

#define B_ 2
#define S_ 2048
#define E_ 1024
#define H_ 16
#define HD_ 64
#define LAMBDA_INIT 0.8f
#define EPS_ 1e-6f

typedef __attribute__((ext_vector_type(8))) short short8;   // 8 bf16 (4 VGPRs)
typedef __attribute__((ext_vector_type(8))) unsigned short ushort8v;
typedef __attribute__((ext_vector_type(4))) float floatx4;  // MFMA C/D 16x16
typedef __attribute__((ext_vector_type(16))) float floatx16; // MFMA C/D 32x32

__device__ __forceinline__ unsigned short f2bf(float f) {
  unsigned u = __float_as_uint(f);
  u += 0x7FFFu + ((u >> 16) & 1u);   // RNE
  return (unsigned short)(u >> 16);
}

__device__ __forceinline__ void gl_lds16(const void* g, void* l) {
  __builtin_amdgcn_global_load_lds((const __attribute__((address_space(1))) void*)g,
                                   (__attribute__((address_space(3))) void*)l,
                                   16, 0, 0);
}

// ---------------------------------------------------------------------------
// prep: fused {cast x -> bf16} + {transpose_cast w_qkv} + {transpose_cast wo}.
// Branch on blockIdx (block-uniform); per-branch code identical to the
// verified cast_bf16 / transpose_cast kernels -> bitwise-identical outputs.
// grid 2048: [0,1024) cast, [1024,1792) w_qkv 48x16, [1792,2048) wo 16x16.
// ---------------------------------------------------------------------------
__global__ __launch_bounds__(256) void prep(const float* __restrict__ x,
                                            const float* __restrict__ w_qkv,
                                            const float* __restrict__ wo,
                                            unsigned short* __restrict__ xB,
                                            unsigned short* __restrict__ WT,
                                            unsigned short* __restrict__ woT) {
  __shared__ float tile[64][65];
  const int tid = threadIdx.x;
  const int bid = blockIdx.x;
  if (bid < 1024) {
    const int n4 = 4096 * 1024 / 4;
    for (int i = bid * 256 + tid; i < n4; i += 1024 * 256) {
      float4 v = ((const float4*)x)[i];
      ushort4 w;
      w.x = f2bf(v.x); w.y = f2bf(v.y); w.z = f2bf(v.z); w.w = f2bf(v.w);
      ((ushort4*)xB)[i] = w;
    }
    return;
  }
  const float* in;
  unsigned short* out;
  int R, C, bx, by;
  if (bid < 1792) {
    in = w_qkv; out = WT; R = 1024; C = 3072;
    int t = bid - 1024; bx = t % 48; by = t / 48;
  } else {
    in = wo; out = woT; R = 1024; C = 1024;
    int t = bid - 1792; bx = t % 16; by = t / 16;
  }
  const int c0 = bx * 64;
  const int r0 = by * 64;
#pragma unroll
  for (int it = 0; it < 16; it++) {
    int e = tid + it * 256;
    int rr = e >> 6, cc = e & 63;
    tile[rr][cc] = in[(size_t)(r0 + rr) * C + c0 + cc];
  }
  __syncthreads();
#pragma unroll
  for (int it = 0; it < 16; it++) {
    int e = tid + it * 256;
    int rr = e >> 6, cc = e & 63;
    out[(size_t)(c0 + rr) * R + r0 + cc] = f2bf(tile[cc][rr]);
  }
}

// ---------------------------------------------------------------------------
// bf16 MFMA GEMM body: C[M][N] = A[M][K] @ B[K][N], B given TRANSPOSED as
// Bt[N][K]. Tile 128 x BNT (BNT = 128 or 64), BK=64, 256 thr (4 waves, 2x2 of
// 64 x BNT/2), global_load_lds w=16, XOR chunk swizzle (c_phys = c_log^(r&7))
// -> ds_read_b128 frags <=2-way. Factored as a device function so the merged
// qkv_gemm dispatch and the standalone gemm_bt share the verified code path.
// ---------------------------------------------------------------------------
template <bool BF16OUT, int BNT>
__device__ __forceinline__ void gemm_body(unsigned short* As, unsigned short* Bs,
                                          const unsigned short* __restrict__ A,
                                          const unsigned short* __restrict__ Bt,
                                          void* __restrict__ C, int M, int N, int K,
                                          int bx, int by) {
  const int tid = threadIdx.x;
  const int wave = tid >> 6, lane = tid & 63;
  const int lane15 = lane & 15, quad = lane >> 4;
  const int m0 = by * 128;
  const int n0 = bx * BNT;
  const int wm = (wave & 1) * 64, wn = (wave >> 1) * (BNT / 2);
  const int NI = BNT / 32;   // n-fragments per wave

  floatx4 acc[4][NI];
#pragma unroll
  for (int mi = 0; mi < 4; mi++)
#pragma unroll
    for (int ni = 0; ni < NI; ni++) acc[mi][ni] = (floatx4)0.0f;

  const int rsA = wave * 32 + (lane >> 3);        // A staging row base (+j*8)
  const int rsB = wave * (BNT / 4) + (lane >> 3); // B staging row base (+j*8)
  const int cph = lane & 7;                       // physical chunk this lane fills

  for (int k0 = 0; k0 < K; k0 += 64) {
    __syncthreads();   // prior iter's fragment reads done
#pragma unroll
    for (int j = 0; j < 4; j++) {
      int r = rsA + j * 8;
      int cl = cph ^ (r & 7);
      gl_lds16(A + (size_t)(m0 + r) * K + k0 + cl * 8, &As[(wave * 32 + j * 8) * 64]);
    }
#pragma unroll
    for (int j = 0; j < BNT / 32; j++) {
      int r = rsB + j * 8;
      int cl = cph ^ (r & 7);
      gl_lds16(Bt + (size_t)(n0 + r) * K + k0 + cl * 8,
               &Bs[(wave * (BNT / 4) + j * 8) * 64]);
    }
    __syncthreads();   // drains vmcnt(0): staged data visible

#pragma unroll
    for (int ks = 0; ks < 2; ks++) {
      short8 af[4], bf[NI];
#pragma unroll
      for (int mi = 0; mi < 4; mi++) {
        int r = wm + mi * 16 + lane15;
        int phys = (ks * 4 + quad) ^ (r & 7);
        af[mi] = *(const short8*)(&As[r * 64 + phys * 8]);
      }
#pragma unroll
      for (int ni = 0; ni < NI; ni++) {
        int r = wn + ni * 16 + lane15;
        int phys = (ks * 4 + quad) ^ (r & 7);
        bf[ni] = *(const short8*)(&Bs[r * 64 + phys * 8]);
      }
#pragma unroll
      for (int mi = 0; mi < 4; mi++)
#pragma unroll
        for (int ni = 0; ni < NI; ni++)
          acc[mi][ni] = __builtin_amdgcn_mfma_f32_16x16x32_bf16(af[mi], bf[ni],
                                                                acc[mi][ni], 0, 0, 0);
    }
  }

#pragma unroll
  for (int mi = 0; mi < 4; mi++)
#pragma unroll
    for (int ni = 0; ni < NI; ni++)
#pragma unroll
      for (int reg = 0; reg < 4; reg++) {
        int row = m0 + wm + mi * 16 + quad * 4 + reg;
        int col = n0 + wn + ni * 16 + lane15;
        float v = acc[mi][ni][reg];
        if (BF16OUT)
          ((unsigned short*)C)[(size_t)row * N + col] = f2bf(v);
        else
          ((float*)C)[(size_t)row * N + col] = v;
      }
}

// standalone GEMM (used for out = hidden @ wo)
template <bool BF16OUT, int BNT>
__global__ __launch_bounds__(256, BNT == 64 ? 2 : 1) void gemm_bt(
    const unsigned short* __restrict__ A, const unsigned short* __restrict__ Bt,
    void* __restrict__ C, int M, int N, int K) {
  __shared__ __align__(16) unsigned short As[128 * 64];
  __shared__ __align__(16) unsigned short Bs[BNT * 64];
  gemm_body<BF16OUT, BNT>(As, Bs, A, Bt, C, M, N, K, blockIdx.x, blockIdx.y);
}

// ---------------------------------------------------------------------------
// qkv_gemm: MERGED {qk = x @ Wqk (BNT=128 path)} + {vT = Wv^T @ x^T (BNT=64
// path)} in one dispatch. The two GEMMs are independent (both read only prep
// outputs, write disjoint buffers); block-uniform branch selects the exact
// previously-verified code path with identical (bx,by) maps -> bitwise-same
// outputs. 1024 blocks co-resident (~3/CU) overlap the skinny v-GEMM's stalls
// under the qk-GEMM's MFMA work and kill one launch gap + one grid tail.
// ---------------------------------------------------------------------------
__global__ __launch_bounds__(256) void qkv_gemm(const unsigned short* __restrict__ xB,
                                                const unsigned short* __restrict__ WT,
                                                unsigned short* __restrict__ qkB,
                                                unsigned short* __restrict__ vTB) {
  __shared__ __align__(16) unsigned short As[128 * 64];
  __shared__ __align__(16) unsigned short Bs[128 * 64];
  const int id = blockIdx.x;
  if (id < 512) {
    // was: gemm_bt<true,128> grid dim3(16, 32)
    gemm_body<true, 128>(As, Bs, xB, WT, qkB, 4096, 2048, 1024, id & 15, id >> 4);
  } else {
    // was: gemm_bt<true,64> grid dim3(64, 8), A = WT + 2048*1024 (Wv^T), B = xB
    const int t = id - 512;
    gemm_body<true, 64>(As, Bs, WT + (size_t)2048 * 1024, xB, vTB, 1024, 4096, 1024,
                        t & 63, t >> 6);
  }
}

// ---------------------------------------------------------------------------
// MFMA flash differential attention, 32x32x16 swapped-QK^T, SPLIT-S waves.
// [Byte-identical to verified R9.] Block = 128 q rows, 512 threads, 8 waves =
// (qsub 0..3) x (sw 0..1); fused RMSNorm + reshape epilogue (bitwise-exact).
// ---------------------------------------------------------------------------
__global__ __launch_bounds__(512, 4) void flash_attn_mfma(
    const unsigned short* __restrict__ qkB, const unsigned short* __restrict__ vTB,
    const float* __restrict__ lq1, const float* __restrict__ lq2,
    const float* __restrict__ lk1, const float* __restrict__ lk2,
    const float* __restrict__ norm_w, unsigned short* __restrict__ hid) {
  __shared__ __align__(16) unsigned short KV[2][2][64 * 64];   // [buf][0=K,1=V]
  __shared__ float Lex[4][64];                                 // sw=1 lsum
  __shared__ float LF2[64][130];                               // [d][q] out tile

  const int tid = threadIdx.x;
  const int wave = tid >> 6, lane = tid & 63;
  const int l31 = lane & 31, hi = lane >> 5;
  const int qsub = wave >> 1, sw = wave & 1;

  // bijective XCD swizzle: the 16 q-tiles sharing one (b,h)'s K/V land on one XCD
  const int bid = (blockIdx.x & 7) * 64 + (blockIdx.x >> 3);   // 512 blocks
  const int qt = bid & 15;
  const int h = (bid >> 4) & 15;
  const int b = bid >> 8;
  const int q0 = qt * 128;

  float a1 = 0.f, a2 = 0.f;
  for (int d = 0; d < HD_; d++) {
    a1 += lq1[d] * lk1[d];
    a2 += lq2[d] * lk2[d];
  }
  const float lam = __expf(a1) - __expf(a2) + LAMBDA_INIT;

  // Q fragments for MY branch: Q[q = q0+qsub*32+l31][h*64 + sw*32 + cs*16 + hi*8]
  short8 qf[2];
  {
    const unsigned short* qrow =
        qkB + (size_t)(b * S_ + q0 + qsub * 32 + l31) * 2048 + h * 64 + sw * 32;
#pragma unroll
    for (int cs = 0; cs < 2; cs++)
      qf[cs] = *(const short8*)(qrow + cs * 16 + hi * 8);
  }

  floatx16 accO[2];
#pragma unroll
  for (int n = 0; n < 2; n++) accO[n] = (floatx16)0.0f;
  float lsum = 0.f;
  const floatx16 zero16 = (floatx16)0.0f;

  const int srow = tid >> 3;   // 512 threads cover all 64 rows in one round
  const int scol = tid & 7;    // physical 16B chunk this lane fills
  const size_t kgbase = (size_t)(b * S_) * 2048 + 1024 + h * 64;
  const size_t vgbase = (size_t)h * 64 * 4096 + b * 2048;

  // stage tile t into buffer buf: 1 K + 1 V gl_lds per thread
#define STAGE(t_, buf_)                                                        \
  {                                                                            \
    const size_t kg_ = kgbase + (size_t)(t_) * 64 * 2048;                      \
    const size_t vg_ = vgbase + (size_t)(t_) * 64;                             \
    const int cl_ = scol ^ (srow & 7);                                         \
    gl_lds16(qkB + kg_ + (size_t)srow * 2048 + cl_ * 8,                        \
             &KV[buf_][0][(wave * 8) * 64]);                                   \
    gl_lds16(vTB + vg_ + (size_t)srow * 4096 + cl_ * 8,                        \
             &KV[buf_][1][(wave * 8) * 64]);                                   \
  }

  // prologue: stage tile 0 into buffer 0
  STAGE(0, 0);
  __syncthreads();

  int cur = 0;
  for (int t = 0; t < S_ / 64; t++) {
    if (t < S_ / 64 - 1) STAGE(t + 1, cur ^ 1);   // async prefetch
    const unsigned short* Kc = &KV[cur][0][0];
    const unsigned short* Vc = &KV[cur][1][0];

#pragma unroll
    for (int kb = 0; kb < 2; kb++) {
      const int krow = kb * 32 + l31;
      const int kx = krow & 7;
      floatx16 accS = zero16;
#pragma unroll
      for (int cs = 0; cs < 2; cs++) {
        const int pc = (sw * 4 + cs * 2 + hi) ^ kx;
        const short8 kf = *(const short8*)(Kc + krow * 64 + pc * 8);
        accS = __builtin_amdgcn_mfma_f32_32x32x16_bf16(kf, qf[cs], accS, 0, 0, 0);
      }
      // accS: q = l31 (col), k row = (reg&3) + 8*(reg>>2) + 4*hi
      unsigned w[8];
      float ls = 0.f;
#pragma unroll
      for (int i = 0; i < 8; i++) {
        float p0 = __expf(accS[2 * i] * 0.125f);
        float p1 = __expf(accS[2 * i + 1] * 0.125f);
        ls += p0 + p1;
        asm("v_cvt_pk_bf16_f32 %0, %1, %2" : "=v"(w[i]) : "v"(p0), "v"(p1));
      }
      lsum += ls;
      // dst.hi <-> src.lo: dst = low k-quad pack, src = high k-quad pack
      asm volatile("v_permlane32_swap_b32 %0, %1" : "+v"(w[0]), "+v"(w[2]));
      asm volatile("v_permlane32_swap_b32 %0, %1" : "+v"(w[1]), "+v"(w[3]));
      asm volatile("v_permlane32_swap_b32 %0, %1" : "+v"(w[4]), "+v"(w[6]));
      asm volatile("v_permlane32_swap_b32 %0, %1" : "+v"(w[5]), "+v"(w[7]));
      uint4 u0 = make_uint4(w[0], w[1], w[2], w[3]);
      uint4 u1 = make_uint4(w[4], w[5], w[6], w[7]);
      short8 pf0 = __builtin_bit_cast(short8, u0);
      short8 pf1 = __builtin_bit_cast(short8, u1);
      // PV for MY branch over this kb
#pragma unroll
      for (int ks2 = 0; ks2 < 2; ks2++) {
        const short8 pa = ks2 ? pf1 : pf0;
#pragma unroll
        for (int n = 0; n < 2; n++) {
          const int vrow = n * 32 + l31;
          const int pc = (kb * 4 + ks2 * 2 + hi) ^ (vrow & 7);
          const short8 vf = *(const short8*)(Vc + vrow * 64 + pc * 8);
          accO[n] = __builtin_amdgcn_mfma_f32_32x32x16_bf16(pa, vf, accO[n], 0, 0, 0);
        }
      }
    }
    __syncthreads();   // drains vmcnt(0): next tile staged; cur free to overwrite
    cur ^= 1;
  }
#undef STAGE

  // finalize row sums (partner lane-half holds complementary k rows)
  lsum += __shfl_xor(lsum, 32, 64);

  // ---- index-matched exchange: sw=1 pushes partials, sw=0 combines ----
  float* LF = (float*)&KV[0][0][0];   // 8192 floats = the dead K/V buffers
  if (sw == 1) {
    Lex[qsub][lane] = lsum;
#pragma unroll
    for (int n = 0; n < 2; n++)
#pragma unroll
      for (int r = 0; r < 16; r++)
        LF[qsub * 2048 + (n * 16 + r) * 64 + lane] = accO[n][r];
  }
  __syncthreads();

  if (sw == 0) {
    const float ls2v = Lex[qsub][lane];
    const float* nw = norm_w + h * HD_;
    const float nw0 = nw[l31], nw1 = nw[32 + l31];
#pragma unroll
    for (int r = 0; r < 16; r++) {
      const int qr = (r & 3) + 8 * (r >> 2) + 4 * hi;   // q row within wave's 32
      const float s1 = __shfl(lsum, qr, 64);
      const float s2 = __shfl(ls2v, qr, 64);
      const float inv1 = 1.0f / s1;
      const float c2 = lam / s2;
      const float b0 = LF[qsub * 2048 + (0 * 16 + r) * 64 + lane];
      const float b1 = LF[qsub * 2048 + (1 * 16 + r) * 64 + lane];
      float o0 = accO[0][r] * inv1 - b0 * c2;   // d = l31
      float o1 = accO[1][r] * inv1 - b1 * c2;   // d = 32 + l31
      float ss = o0 * o0 + o1 * o1;
#pragma unroll
      for (int msk = 1; msk <= 16; msk <<= 1) ss += __shfl_xor(ss, msk, 64);
      const float rsc = (1.0f - LAMBDA_INIT) * rsqrtf(ss * (1.0f / 64.0f) + EPS_);
      LF2[l31][qsub * 32 + qr] = o0 * rsc * nw0;        // fp32 staging (exact)
      LF2[32 + l31][qsub * 32 + qr] = o1 * rsc * nw1;
    }
  }
  __syncthreads();

  // ---- fused reshape: all 512 threads, d-major coalesced bf16 store ----
  // hidden[b*S*E + d*H*S + h*S + (q0 + qq)] = bf16(LF2[d][qq])
  {
    const int d = tid >> 3, g = tid & 7;
    unsigned short* dst =
        hid + (size_t)b * (S_ * E_) + (size_t)d * (H_ * S_) + h * S_ + q0 + g * 16;
    ushort8v v0, v1;
#pragma unroll
    for (int j = 0; j < 8; j++) {
      v0[j] = f2bf(LF2[d][g * 16 + j]);
      v1[j] = f2bf(LF2[d][g * 16 + 8 + j]);
    }
    *(ushort8v*)(dst) = v0;
    *(ushort8v*)(dst + 8) = v1;
  }
}

// ---------------------------------------------------------------------------
extern "C" void kernel_launch(void* const* d_in, const int* in_sizes, int n_in,
                              void* d_out, int out_size, void* d_ws, size_t ws_size,
                              hipStream_t stream) {
  const float* x = (const float*)d_in[0];
  const float* w_qkv = (const float*)d_in[1];
  const float* wo = (const float*)d_in[2];
  const float* lq1 = (const float*)d_in[3];
  const float* lq2 = (const float*)d_in[4];
  const float* lk1 = (const float*)d_in[5];
  const float* lk2 = (const float*)d_in[6];
  const float* norm_w = (const float*)d_in[7];
  float* out = (float*)d_out;

  unsigned short* xB = (unsigned short*)d_ws;             // 4096*1024
  unsigned short* WT = xB + (size_t)4096 * 1024;          // 3072*1024 (w_qkv^T)
  unsigned short* woT = WT + (size_t)3072 * 1024;         // 1024*1024
  unsigned short* qkB = woT + (size_t)1024 * 1024;        // 4096*2048
  unsigned short* vTB = qkB + (size_t)4096 * 2048;        // 1024*4096
  unsigned short* hidB = vTB + (size_t)1024 * 4096;       // 4096*1024

  // 0) fused bf16 cast + transposes of inputs (one launch)
  prep<<<2048, 256, 0, stream>>>(x, w_qkv, wo, xB, WT, woT);

  // 1) MERGED: {q,k = x @ Wqk -> qkB} + {vT = Wv^T @ x^T -> vTB} (1024 blocks)
  qkv_gemm<<<1024, 256, 0, stream>>>(xB, WT, qkB, vTB);

  // 2) MFMA differential flash attention + RMSNorm + fused reshape -> hidB bf16
  flash_attn_mfma<<<B_ * H_ * (S_ / 128), 512, 0, stream>>>(qkB, vTB, lq1, lq2, lk1,
                                                            lk2, norm_w, hidB);
  // 3) out = hidden @ wo (fp32 out)  (128x64 tile: 512 blocks, 2 blocks/CU)
  gemm_bt<false, 64><<<dim3(1024 / 64, 4096 / 128), 256, 0, stream>>>(
      hidB, woT, (void*)out, 4096, 1024, 1024);
}

// Round 12
// 219.410 us; speedup vs baseline: 1.2942x; 1.0298x over previous
//
#include <hip/hip_runtime.h>
#include <math.h>

#define B_ 2
#define S_ 2048
#define E_ 1024
#define H_ 16
#define HD_ 64
#define LAMBDA_INIT 0.8f
#define EPS_ 1e-6f

typedef __attribute__((ext_vector_type(8))) short short8;   // 8 bf16 (4 VGPRs)
typedef __attribute__((ext_vector_type(8))) unsigned short ushort8v;
typedef __attribute__((ext_vector_type(4))) float floatx4;  // MFMA C/D 16x16
typedef __attribute__((ext_vector_type(16))) float floatx16; // MFMA C/D 32x32

__device__ __forceinline__ unsigned short f2bf(float f) {
  unsigned u = __float_as_uint(f);
  u += 0x7FFFu + ((u >> 16) & 1u);   // RNE
  return (unsigned short)(u >> 16);
}

__device__ __forceinline__ void gl_lds16(const void* g, void* l) {
  __builtin_amdgcn_global_load_lds((const __attribute__((address_space(1))) void*)g,
                                   (__attribute__((address_space(3))) void*)l,
                                   16, 0, 0);
}

// ---------------------------------------------------------------------------
// prep: fused {cast x -> bf16} + {transpose_cast w_qkv} + {transpose_cast wo}.
// [Byte-identical to verified R10.]
// ---------------------------------------------------------------------------
__global__ __launch_bounds__(256) void prep(const float* __restrict__ x,
                                            const float* __restrict__ w_qkv,
                                            const float* __restrict__ wo,
                                            unsigned short* __restrict__ xB,
                                            unsigned short* __restrict__ WT,
                                            unsigned short* __restrict__ woT) {
  __shared__ float tile[64][65];
  const int tid = threadIdx.x;
  const int bid = blockIdx.x;
  if (bid < 1024) {
    const int n4 = 4096 * 1024 / 4;
    for (int i = bid * 256 + tid; i < n4; i += 1024 * 256) {
      float4 v = ((const float4*)x)[i];
      ushort4 w;
      w.x = f2bf(v.x); w.y = f2bf(v.y); w.z = f2bf(v.z); w.w = f2bf(v.w);
      ((ushort4*)xB)[i] = w;
    }
    return;
  }
  const float* in;
  unsigned short* out;
  int R, C, bx, by;
  if (bid < 1792) {
    in = w_qkv; out = WT; R = 1024; C = 3072;
    int t = bid - 1024; bx = t % 48; by = t / 48;
  } else {
    in = wo; out = woT; R = 1024; C = 1024;
    int t = bid - 1792; bx = t % 16; by = t / 16;
  }
  const int c0 = bx * 64;
  const int r0 = by * 64;
#pragma unroll
  for (int it = 0; it < 16; it++) {
    int e = tid + it * 256;
    int rr = e >> 6, cc = e & 63;
    tile[rr][cc] = in[(size_t)(r0 + rr) * C + c0 + cc];
  }
  __syncthreads();
#pragma unroll
  for (int it = 0; it < 16; it++) {
    int e = tid + it * 256;
    int rr = e >> 6, cc = e & 63;
    out[(size_t)(c0 + rr) * R + r0 + cc] = f2bf(tile[cc][rr]);
  }
}

// ---------------------------------------------------------------------------
// bf16 MFMA GEMM body: C[M][N] = A[M][K] @ B[K][N], B given TRANSPOSED as
// Bt[N][K]. Tile 128 x BNT, BK=64, 256 thr (4 waves), global_load_lds w=16,
// XOR chunk swizzle. CHANGED (R12): 1-barrier DOUBLE-BUFFER K-loop -- the
// exact structure flash_attn has used (verified) since R2: prologue-stage
// buf0; loop { stage k0+64 -> buf^1, compute buf, __syncthreads (drains
// vmcnt) }. Loads overlap compute instead of a bare issue->drain window.
// Same loads, same K-accumulation order -> bitwise-identical C.
// ---------------------------------------------------------------------------
template <bool BF16OUT, int BNT>
__device__ __forceinline__ void gemm_body(unsigned short* AsB, unsigned short* BsB,
                                          const unsigned short* __restrict__ A,
                                          const unsigned short* __restrict__ Bt,
                                          void* __restrict__ C, int M, int N, int K,
                                          int bx, int by) {
  const int tid = threadIdx.x;
  const int wave = tid >> 6, lane = tid & 63;
  const int lane15 = lane & 15, quad = lane >> 4;
  const int m0 = by * 128;
  const int n0 = bx * BNT;
  const int wm = (wave & 1) * 64, wn = (wave >> 1) * (BNT / 2);
  const int NI = BNT / 32;   // n-fragments per wave

  floatx4 acc[4][NI];
#pragma unroll
  for (int mi = 0; mi < 4; mi++)
#pragma unroll
    for (int ni = 0; ni < NI; ni++) acc[mi][ni] = (floatx4)0.0f;

  const int rsA = wave * 32 + (lane >> 3);        // A staging row base (+j*8)
  const int rsB = wave * (BNT / 4) + (lane >> 3); // B staging row base (+j*8)
  const int cph = lane & 7;                       // physical chunk this lane fills

#define GSTAGE(k0_, As_, Bs_)                                                  \
  {                                                                            \
    _Pragma("unroll")                                                          \
    for (int j = 0; j < 4; j++) {                                              \
      int r = rsA + j * 8;                                                     \
      int cl = cph ^ (r & 7);                                                  \
      gl_lds16(A + (size_t)(m0 + r) * K + (k0_) + cl * 8,                      \
               (As_) + (wave * 32 + j * 8) * 64);                              \
    }                                                                          \
    _Pragma("unroll")                                                          \
    for (int j = 0; j < BNT / 32; j++) {                                       \
      int r = rsB + j * 8;                                                     \
      int cl = cph ^ (r & 7);                                                  \
      gl_lds16(Bt + (size_t)(n0 + r) * K + (k0_) + cl * 8,                     \
               (Bs_) + (wave * (BNT / 4) + j * 8) * 64);                       \
    }                                                                          \
  }

  // prologue: stage k-tile 0 into buffer 0 (__syncthreads drains vmcnt(0))
  GSTAGE(0, AsB, BsB);
  __syncthreads();

  int cur = 0;
  for (int k0 = 0; k0 < K; k0 += 64) {
    if (k0 + 64 < K)
      GSTAGE(k0 + 64, AsB + (cur ^ 1) * (128 * 64), BsB + (cur ^ 1) * (BNT * 64));
    const unsigned short* As = AsB + cur * (128 * 64);
    const unsigned short* Bs = BsB + cur * (BNT * 64);

#pragma unroll
    for (int ks = 0; ks < 2; ks++) {
      short8 af[4], bf[NI];
#pragma unroll
      for (int mi = 0; mi < 4; mi++) {
        int r = wm + mi * 16 + lane15;
        int phys = (ks * 4 + quad) ^ (r & 7);
        af[mi] = *(const short8*)(&As[r * 64 + phys * 8]);
      }
#pragma unroll
      for (int ni = 0; ni < NI; ni++) {
        int r = wn + ni * 16 + lane15;
        int phys = (ks * 4 + quad) ^ (r & 7);
        bf[ni] = *(const short8*)(&Bs[r * 64 + phys * 8]);
      }
#pragma unroll
      for (int mi = 0; mi < 4; mi++)
#pragma unroll
        for (int ni = 0; ni < NI; ni++)
          acc[mi][ni] = __builtin_amdgcn_mfma_f32_16x16x32_bf16(af[mi], bf[ni],
                                                                acc[mi][ni], 0, 0, 0);
    }
    __syncthreads();   // drains vmcnt(0): next tile staged; cur reads done
    cur ^= 1;
  }
#undef GSTAGE

#pragma unroll
  for (int mi = 0; mi < 4; mi++)
#pragma unroll
    for (int ni = 0; ni < NI; ni++)
#pragma unroll
      for (int reg = 0; reg < 4; reg++) {
        int row = m0 + wm + mi * 16 + quad * 4 + reg;
        int col = n0 + wn + ni * 16 + lane15;
        float v = acc[mi][ni][reg];
        if (BF16OUT)
          ((unsigned short*)C)[(size_t)row * N + col] = f2bf(v);
        else
          ((float*)C)[(size_t)row * N + col] = v;
      }
}

template <bool BF16OUT, int BNT>
__global__ __launch_bounds__(256, BNT == 64 ? 2 : 1) void gemm_bt(
    const unsigned short* __restrict__ A, const unsigned short* __restrict__ Bt,
    void* __restrict__ C, int M, int N, int K) {
  __shared__ __align__(16) unsigned short As[2 * 128 * 64];
  __shared__ __align__(16) unsigned short Bs[2 * BNT * 64];
  gemm_body<BF16OUT, BNT>(As, Bs, A, Bt, C, M, N, K, blockIdx.x, blockIdx.y);
}

__global__ __launch_bounds__(256) void qkv_gemm(const unsigned short* __restrict__ xB,
                                                const unsigned short* __restrict__ WT,
                                                unsigned short* __restrict__ qkB,
                                                unsigned short* __restrict__ vTB) {
  __shared__ __align__(16) unsigned short As[2 * 128 * 64];
  __shared__ __align__(16) unsigned short Bs[2 * 128 * 64];
  const int id = blockIdx.x;
  if (id < 512) {
    gemm_body<true, 128>(As, Bs, xB, WT, qkB, 4096, 2048, 1024, id & 15, id >> 4);
  } else {
    const int t = id - 512;
    gemm_body<true, 64>(As, Bs, WT + (size_t)2048 * 1024, xB, vTB, 1024, 4096, 1024,
                        t & 63, t >> 6);
  }
}

// ---------------------------------------------------------------------------
// MFMA flash differential attention, 32x32x16 swapped-QK^T, SPLIT-S waves.
// [Byte-identical to verified R9/R10.] Block = 128 q rows, 512 threads,
// 8 waves = (qsub 0..3) x (sw 0..1); fused RMSNorm + reshape epilogue.
// NOTE: split-kb (16 waves) failed correctness twice (R3, R11) with no
// statically locatable bug -- that axis is retired; do not re-attempt blind.
// ---------------------------------------------------------------------------
__global__ __launch_bounds__(512, 4) void flash_attn_mfma(
    const unsigned short* __restrict__ qkB, const unsigned short* __restrict__ vTB,
    const float* __restrict__ lq1, const float* __restrict__ lq2,
    const float* __restrict__ lk1, const float* __restrict__ lk2,
    const float* __restrict__ norm_w, unsigned short* __restrict__ hid) {
  __shared__ __align__(16) unsigned short KV[2][2][64 * 64];   // [buf][0=K,1=V]
  __shared__ float Lex[4][64];                                 // sw=1 lsum
  __shared__ float LF2[64][130];                               // [d][q] out tile

  const int tid = threadIdx.x;
  const int wave = tid >> 6, lane = tid & 63;
  const int l31 = lane & 31, hi = lane >> 5;
  const int qsub = wave >> 1, sw = wave & 1;

  // bijective XCD swizzle: the 16 q-tiles sharing one (b,h)'s K/V land on one XCD
  const int bid = (blockIdx.x & 7) * 64 + (blockIdx.x >> 3);   // 512 blocks
  const int qt = bid & 15;
  const int h = (bid >> 4) & 15;
  const int b = bid >> 8;
  const int q0 = qt * 128;

  float a1 = 0.f, a2 = 0.f;
  for (int d = 0; d < HD_; d++) {
    a1 += lq1[d] * lk1[d];
    a2 += lq2[d] * lk2[d];
  }
  const float lam = __expf(a1) - __expf(a2) + LAMBDA_INIT;

  // Q fragments for MY branch: Q[q = q0+qsub*32+l31][h*64 + sw*32 + cs*16 + hi*8]
  short8 qf[2];
  {
    const unsigned short* qrow =
        qkB + (size_t)(b * S_ + q0 + qsub * 32 + l31) * 2048 + h * 64 + sw * 32;
#pragma unroll
    for (int cs = 0; cs < 2; cs++)
      qf[cs] = *(const short8*)(qrow + cs * 16 + hi * 8);
  }

  floatx16 accO[2];
#pragma unroll
  for (int n = 0; n < 2; n++) accO[n] = (floatx16)0.0f;
  float lsum = 0.f;
  const floatx16 zero16 = (floatx16)0.0f;

  const int srow = tid >> 3;   // 512 threads cover all 64 rows in one round
  const int scol = tid & 7;    // physical 16B chunk this lane fills
  const size_t kgbase = (size_t)(b * S_) * 2048 + 1024 + h * 64;
  const size_t vgbase = (size_t)h * 64 * 4096 + b * 2048;

  // stage tile t into buffer buf: 1 K + 1 V gl_lds per thread
#define STAGE(t_, buf_)                                                        \
  {                                                                            \
    const size_t kg_ = kgbase + (size_t)(t_) * 64 * 2048;                      \
    const size_t vg_ = vgbase + (size_t)(t_) * 64;                             \
    const int cl_ = scol ^ (srow & 7);                                         \
    gl_lds16(qkB + kg_ + (size_t)srow * 2048 + cl_ * 8,                        \
             &KV[buf_][0][(wave * 8) * 64]);                                   \
    gl_lds16(vTB + vg_ + (size_t)srow * 4096 + cl_ * 8,                        \
             &KV[buf_][1][(wave * 8) * 64]);                                   \
  }

  // prologue: stage tile 0 into buffer 0
  STAGE(0, 0);
  __syncthreads();

  int cur = 0;
  for (int t = 0; t < S_ / 64; t++) {
    if (t < S_ / 64 - 1) STAGE(t + 1, cur ^ 1);   // async prefetch
    const unsigned short* Kc = &KV[cur][0][0];
    const unsigned short* Vc = &KV[cur][1][0];

#pragma unroll
    for (int kb = 0; kb < 2; kb++) {
      const int krow = kb * 32 + l31;
      const int kx = krow & 7;
      floatx16 accS = zero16;
#pragma unroll
      for (int cs = 0; cs < 2; cs++) {
        const int pc = (sw * 4 + cs * 2 + hi) ^ kx;
        const short8 kf = *(const short8*)(Kc + krow * 64 + pc * 8);
        accS = __builtin_amdgcn_mfma_f32_32x32x16_bf16(kf, qf[cs], accS, 0, 0, 0);
      }
      // accS: q = l31 (col), k row = (reg&3) + 8*(reg>>2) + 4*hi
      unsigned w[8];
      float ls = 0.f;
#pragma unroll
      for (int i = 0; i < 8; i++) {
        float p0 = __expf(accS[2 * i] * 0.125f);
        float p1 = __expf(accS[2 * i + 1] * 0.125f);
        ls += p0 + p1;
        asm("v_cvt_pk_bf16_f32 %0, %1, %2" : "=v"(w[i]) : "v"(p0), "v"(p1));
      }
      lsum += ls;
      // dst.hi <-> src.lo: dst = low k-quad pack, src = high k-quad pack
      asm volatile("v_permlane32_swap_b32 %0, %1" : "+v"(w[0]), "+v"(w[2]));
      asm volatile("v_permlane32_swap_b32 %0, %1" : "+v"(w[1]), "+v"(w[3]));
      asm volatile("v_permlane32_swap_b32 %0, %1" : "+v"(w[4]), "+v"(w[6]));
      asm volatile("v_permlane32_swap_b32 %0, %1" : "+v"(w[5]), "+v"(w[7]));
      uint4 u0 = make_uint4(w[0], w[1], w[2], w[3]);
      uint4 u1 = make_uint4(w[4], w[5], w[6], w[7]);
      short8 pf0 = __builtin_bit_cast(short8, u0);
      short8 pf1 = __builtin_bit_cast(short8, u1);
      // PV for MY branch over this kb
#pragma unroll
      for (int ks2 = 0; ks2 < 2; ks2++) {
        const short8 pa = ks2 ? pf1 : pf0;
#pragma unroll
        for (int n = 0; n < 2; n++) {
          const int vrow = n * 32 + l31;
          const int pc = (kb * 4 + ks2 * 2 + hi) ^ (vrow & 7);
          const short8 vf = *(const short8*)(Vc + vrow * 64 + pc * 8);
          accO[n] = __builtin_amdgcn_mfma_f32_32x32x16_bf16(pa, vf, accO[n], 0, 0, 0);
        }
      }
    }
    __syncthreads();   // drains vmcnt(0): next tile staged; cur free to overwrite
    cur ^= 1;
  }
#undef STAGE

  // finalize row sums (partner lane-half holds complementary k rows)
  lsum += __shfl_xor(lsum, 32, 64);

  // ---- index-matched exchange: sw=1 pushes partials, sw=0 combines ----
  float* LF = (float*)&KV[0][0][0];   // 8192 floats = the dead K/V buffers
  if (sw == 1) {
    Lex[qsub][lane] = lsum;
#pragma unroll
    for (int n = 0; n < 2; n++)
#pragma unroll
      for (int r = 0; r < 16; r++)
        LF[qsub * 2048 + (n * 16 + r) * 64 + lane] = accO[n][r];
  }
  __syncthreads();

  if (sw == 0) {
    const float ls2v = Lex[qsub][lane];
    const float* nw = norm_w + h * HD_;
    const float nw0 = nw[l31], nw1 = nw[32 + l31];
#pragma unroll
    for (int r = 0; r < 16; r++) {
      const int qr = (r & 3) + 8 * (r >> 2) + 4 * hi;   // q row within wave's 32
      const float s1 = __shfl(lsum, qr, 64);
      const float s2 = __shfl(ls2v, qr, 64);
      const float inv1 = 1.0f / s1;
      const float c2 = lam / s2;
      const float b0 = LF[qsub * 2048 + (0 * 16 + r) * 64 + lane];
      const float b1 = LF[qsub * 2048 + (1 * 16 + r) * 64 + lane];
      float o0 = accO[0][r] * inv1 - b0 * c2;   // d = l31
      float o1 = accO[1][r] * inv1 - b1 * c2;   // d = 32 + l31
      float ss = o0 * o0 + o1 * o1;
#pragma unroll
      for (int msk = 1; msk <= 16; msk <<= 1) ss += __shfl_xor(ss, msk, 64);
      const float rsc = (1.0f - LAMBDA_INIT) * rsqrtf(ss * (1.0f / 64.0f) + EPS_);
      LF2[l31][qsub * 32 + qr] = o0 * rsc * nw0;        // fp32 staging (exact)
      LF2[32 + l31][qsub * 32 + qr] = o1 * rsc * nw1;
    }
  }
  __syncthreads();

  // ---- fused reshape: all 512 threads, d-major coalesced bf16 store ----
  // hidden[b*S*E + d*H*S + h*S + (q0 + qq)] = bf16(LF2[d][qq])
  {
    const int d = tid >> 3, g = tid & 7;
    unsigned short* dst =
        hid + (size_t)b * (S_ * E_) + (size_t)d * (H_ * S_) + h * S_ + q0 + g * 16;
    ushort8v v0, v1;
#pragma unroll
    for (int j = 0; j < 8; j++) {
      v0[j] = f2bf(LF2[d][g * 16 + j]);
      v1[j] = f2bf(LF2[d][g * 16 + 8 + j]);
    }
    *(ushort8v*)(dst) = v0;
    *(ushort8v*)(dst + 8) = v1;
  }
}

// ---------------------------------------------------------------------------
extern "C" void kernel_launch(void* const* d_in, const int* in_sizes, int n_in,
                              void* d_out, int out_size, void* d_ws, size_t ws_size,
                              hipStream_t stream) {
  const float* x = (const float*)d_in[0];
  const float* w_qkv = (const float*)d_in[1];
  const float* wo = (const float*)d_in[2];
  const float* lq1 = (const float*)d_in[3];
  const float* lq2 = (const float*)d_in[4];
  const float* lk1 = (const float*)d_in[5];
  const float* lk2 = (const float*)d_in[6];
  const float* norm_w = (const float*)d_in[7];
  float* out = (float*)d_out;

  unsigned short* xB = (unsigned short*)d_ws;             // 4096*1024
  unsigned short* WT = xB + (size_t)4096 * 1024;          // 3072*1024 (w_qkv^T)
  unsigned short* woT = WT + (size_t)3072 * 1024;         // 1024*1024
  unsigned short* qkB = woT + (size_t)1024 * 1024;        // 4096*2048
  unsigned short* vTB = qkB + (size_t)4096 * 2048;        // 1024*4096
  unsigned short* hidB = vTB + (size_t)1024 * 4096;       // 4096*1024

  // 0) fused bf16 cast + transposes of inputs (one launch)
  prep<<<2048, 256, 0, stream>>>(x, w_qkv, wo, xB, WT, woT);

  // 1) MERGED: {q,k = x @ Wqk -> qkB} + {vT = Wv^T @ x^T -> vTB} (1024 blocks)
  qkv_gemm<<<1024, 256, 0, stream>>>(xB, WT, qkB, vTB);

  // 2) MFMA differential flash attention + RMSNorm + fused reshape -> hidB bf16
  flash_attn_mfma<<<B_ * H_ * (S_ / 128), 512, 0, stream>>>(qkB, vTB, lq1, lq2, lk1,
                                                            lk2, norm_w, hidB);
  // 3) out = hidden @ wo (fp32 out)  (128x64 tile: 512 blocks, 2 blocks/CU)
  gemm_bt<false, 64><<<dim3(1024 / 64, 4096 / 128), 256, 0, stream>>>(
      hidB, woT, (void*)out, 4096, 1024, 1024);
}